// Round 9
// baseline (297.432 us; speedup 1.0000x reference)
//
#include <hip/hip_runtime.h>
#include <hip/hip_bf16.h>
#include <math.h>

#define T_TOK   2048
#define NHEADS  16
#define EPS_    1e-6f
#define THETA_  10000.0f

typedef __attribute__((ext_vector_type(8))) short short8v;
typedef __attribute__((ext_vector_type(4))) float f32x4;

__device__ inline unsigned short f2bf(float f) {
    union { float f; unsigned u; } v; v.f = f;
    unsigned r = v.u + 0x7fffu + ((v.u >> 16) & 1u);
    return (unsigned short)(r >> 16);
}

// async global->LDS, 16B per lane; LDS dest is wave-uniform base + lane*16
__device__ __forceinline__ void gload16(const unsigned short* src, unsigned short* lds) {
    __builtin_amdgcn_global_load_lds(
        (const __attribute__((address_space(1))) unsigned int*)src,
        (__attribute__((address_space(3))) unsigned int*)lds, 16, 0, 0);
}

// ---------------- block-wide reduce (256 threads = 4 waves) ----------------
__device__ inline float block_reduce(float v, bool is_max, float* sred) {
    #pragma unroll
    for (int off = 32; off > 0; off >>= 1) {
        float o = __shfl_down(v, off, 64);
        v = is_max ? fmaxf(v, o) : (v + o);
    }
    int tid = threadIdx.x;
    __syncthreads();
    if ((tid & 63) == 0) sred[tid >> 6] = v;
    __syncthreads();
    float r = sred[0];
    #pragma unroll
    for (int w = 1; w < 4; ++w) r = is_max ? fmaxf(r, sred[w]) : (r + sred[w]);
    return r;
}

// ---------------- fp32 -> bf16 elementwise (n4 = n/4) ----------------
__global__ __launch_bounds__(256) void conv_bf16(const float* __restrict__ in,
    unsigned short* __restrict__ out, int n4)
{
    int i = blockIdx.x * 256 + threadIdx.x;
    if (i >= n4) return;
    float4 v = ((const float4*)in)[i];
    ushort4 o;
    o.x = f2bf(v.x); o.y = f2bf(v.y); o.z = f2bf(v.z); o.w = f2bf(v.w);
    ((ushort4*)out)[i] = o;
}

// ------------- fp32 [R][C] -> bf16 transposed [C][R] -------------
__global__ __launch_bounds__(256) void wt_bf16(const float* __restrict__ W,
    unsigned short* __restrict__ Wt, int R, int C)
{
    __shared__ float tile[32][33];
    int c0 = blockIdx.x * 32, r0 = blockIdx.y * 32;
    int tx = threadIdx.x & 31, ty = threadIdx.x >> 5;  // ty 0..7
    #pragma unroll
    for (int i = 0; i < 4; ++i)
        tile[ty + i * 8][tx] = W[(size_t)(r0 + ty + i * 8) * C + c0 + tx];
    __syncthreads();
    #pragma unroll
    for (int i = 0; i < 4; ++i)
        Wt[(size_t)(c0 + ty + i * 8) * R + r0 + tx] = f2bf(tile[tx][ty + i * 8]);
}

// =============== bf16 MFMA GEMM: C[M,N] = A[M,K] * Bt[N,K]^T ===============
// 128x128 tile, BK=64, 4 waves; global_load_lds staging + double buffer.
template<bool BF16OUT>
__global__ __launch_bounds__(256) void gemm_bf16(
    const unsigned short* __restrict__ A,   // [M][K] bf16
    const unsigned short* __restrict__ Bt,  // [>=gridX*128][K] bf16
    void* __restrict__ Cv, int N, int K, int ldc)
{
    __shared__ __align__(16) unsigned short As[2][128 * 64];
    __shared__ __align__(16) unsigned short Bs[2][128 * 64];
    const int tid = threadIdx.x;
    const int lane = tid & 63, wid = tid >> 6;
    const int wr = wid >> 1, wc = wid & 1;
    const int lrow = lane & 15, lkg = lane >> 4;
    const int r0 = blockIdx.y * 128, c0 = blockIdx.x * 128;

    f32x4 acc[4][4];
    #pragma unroll
    for (int m = 0; m < 4; ++m)
        #pragma unroll
        for (int n = 0; n < 4; ++n) acc[m][n] = (f32x4)0.f;

    // per-pass staging: unit u = p*256+tid -> row r=u>>3, chunk cu=u&7
    // global src is inverse-swizzled; LDS dest linear (wave-uniform base).
    #define STAGE_GEMM(buf, k0)                                                   \
        {   _Pragma("unroll")                                                     \
            for (int p = 0; p < 4; ++p) {                                         \
                int u = p * 256 + tid;                                            \
                int r = u >> 3, cu = u & 7;                                       \
                int dst = (p * 256 + wid * 64) * 8;                               \
                gload16(A  + (size_t)(r0 + r) * K + (k0) + ((cu ^ (r & 7)) << 3), \
                        As[buf] + dst);                                           \
                gload16(Bt + (size_t)(c0 + r) * K + (k0) + ((cu ^ (r & 7)) << 3), \
                        Bs[buf] + dst);                                           \
            }                                                                     \
        }

    STAGE_GEMM(0, 0)
    __syncthreads();

    const int nkt = K >> 6;
    int buf = 0;
    for (int kt = 0; kt < nkt; ++kt) {
        if (kt + 1 < nkt) STAGE_GEMM(buf ^ 1, (kt + 1) << 6)
        #pragma unroll
        for (int ks = 0; ks < 2; ++ks) {
            short8v af[4], bf[4];
            #pragma unroll
            for (int m = 0; m < 4; ++m) {
                int row = wr * 64 + m * 16 + lrow;
                af[m] = *(const short8v*)((char*)As[buf] + row * 128 + (((ks * 4 + lkg) ^ (row & 7)) << 4));
            }
            #pragma unroll
            for (int n = 0; n < 4; ++n) {
                int row = wc * 64 + n * 16 + lrow;
                bf[n] = *(const short8v*)((char*)Bs[buf] + row * 128 + (((ks * 4 + lkg) ^ (row & 7)) << 4));
            }
            __builtin_amdgcn_s_setprio(1);
            #pragma unroll
            for (int m = 0; m < 4; ++m)
                #pragma unroll
                for (int n = 0; n < 4; ++n)
                    acc[m][n] = __builtin_amdgcn_mfma_f32_16x16x32_bf16(af[m], bf[n], acc[m][n], 0, 0, 0);
            __builtin_amdgcn_s_setprio(0);
        }
        __syncthreads();   // drains vmcnt: next tile staged; buf reads done
        buf ^= 1;
    }
    #undef STAGE_GEMM

    // D layout: col = lane&15, row = (lane>>4)*4 + j
    #pragma unroll
    for (int m = 0; m < 4; ++m) {
        int grow = r0 + wr * 64 + m * 16 + lkg * 4;
        #pragma unroll
        for (int n = 0; n < 4; ++n) {
            int gcol = c0 + wc * 64 + n * 16 + lrow;
            if (gcol < N) {
                #pragma unroll
                for (int j = 0; j < 4; ++j) {
                    if (BF16OUT)
                        ((unsigned short*)Cv)[(size_t)(grow + j) * ldc + gcol] = f2bf(acc[m][n][j]);
                    else
                        ((float*)Cv)[(size_t)(grow + j) * ldc + gcol] = acc[m][n][j];
                }
            }
        }
    }
}

// ---------------- RMSNorm rows -> bf16 ----------------
__global__ __launch_bounds__(256) void rmsnorm_bf16(const float* __restrict__ y,
    const float* __restrict__ g, unsigned short* __restrict__ o, int width)
{
    __shared__ float sred[4];
    int row = blockIdx.x;
    const float* p = y + (size_t)row * width;
    float ss = 0.f;
    for (int i = threadIdx.x; i < width; i += 256) { float v = p[i]; ss += v * v; }
    ss = block_reduce(ss, false, sred);
    float sc = rsqrtf(ss / (float)width + EPS_);
    for (int i = threadIdx.x; i < width; i += 256)
        o[(size_t)row * width + i] = f2bf(p[i] * sc * g[i]);
}

// -- kv row: rmsnorm first 512 -> bf16 out ; RoPE cols 512..575 fp32 inplace --
__global__ __launch_bounds__(256) void kv_fuse(float* __restrict__ kv,
    const float* __restrict__ g, const int* __restrict__ positions,
    unsigned short* __restrict__ kvcb)
{
    __shared__ float sred[4];
    int row = blockIdx.x;
    float* p = kv + (size_t)row * 576;
    float ss = 0.f;
    for (int i = threadIdx.x; i < 512; i += 256) { float v = p[i]; ss += v * v; }
    ss = block_reduce(ss, false, sred);
    float sc = rsqrtf(ss / 512.0f + EPS_);
    for (int i = threadIdx.x; i < 512; i += 256)
        kvcb[(size_t)row * 512 + i] = f2bf(p[i] * sc * g[i]);
    if (threadIdx.x < 32) {
        int i = threadIdx.x;
        float pos = (float)positions[row];
        float inv = powf(THETA_, -(float)i / 32.0f);
        float ang = pos * inv;
        float c = cosf(ang), s = sinf(ang);
        float x1 = p[512 + i], x2 = p[544 + i];
        p[512 + i] = x1 * c - x2 * s;
        p[544 + i] = x2 * c + x1 * s;
    }
}

// -------- RoPE + scale + bf16 pack of q: [T][3072] f32 -> [T][16][192] bf16 --------
__global__ __launch_bounds__(192) void rope_qb(const float* __restrict__ q,
    const int* __restrict__ positions, unsigned short* __restrict__ qb)
{
    int t = blockIdx.x, d = threadIdx.x;
    const float scale = 0.07216878364870323f;  // (128+64)^-0.5
    float c = 1.f, s = 0.f;
    if (d >= 128) {
        int i = (d - 128) & 31;
        float pos = (float)positions[t];
        float inv = powf(THETA_, -(float)i / 32.0f);
        float ang = pos * inv;
        c = cosf(ang); s = sinf(ang);
    }
    #pragma unroll 4
    for (int n = 0; n < 16; ++n) {
        const float* p = q + (size_t)t * 3072 + n * 192;
        float v;
        if (d < 128)      v = p[d];
        else if (d < 160) v = p[d] * c - p[d + 32] * s;
        else              v = p[d] * c + p[d - 32] * s;
        qb[((size_t)t * 16 + n) * 192 + d] = f2bf(v * scale);
    }
}

// -------- K cache: [16][T][192] bf16 = k_nope (from kvb bf16) + roped k_pe --------
__global__ __launch_bounds__(256) void repack_k(const unsigned short* __restrict__ kvbb,
    const float* __restrict__ kv, unsigned short* __restrict__ Kc)
{
    int t = blockIdx.x, tid = threadIdx.x;
    int n = tid >> 4;
    int c8 = tid & 15;
    short8v v = *(const short8v*)(kvbb + ((size_t)t * 16 + n) * 256 + c8 * 8);
    *(short8v*)(Kc + ((size_t)n * 2048 + t) * 192 + c8 * 8) = v;
    int i4 = (tid & 15) * 4;
    float4 p = *(const float4*)(kv + (size_t)t * 576 + 512 + i4);
    ushort4 o; o.x = f2bf(p.x); o.y = f2bf(p.y); o.z = f2bf(p.z); o.w = f2bf(p.w);
    *(ushort4*)(Kc + ((size_t)n * 2048 + t) * 192 + 128 + i4) = o;
}

// -------- V^T cache: [16][128][T] bf16, LDS-tiled 64x64 transpose --------
__global__ __launch_bounds__(256) void repack_vt(const unsigned short* __restrict__ kvbb,
    unsigned short* __restrict__ Vtc)
{
    __shared__ unsigned short tile[64][72];
    int t0 = blockIdx.x * 64;
    int n = blockIdx.y >> 1, dv0 = (blockIdx.y & 1) * 64;
    int tid = threadIdx.x;
    for (int u = tid; u < 512; u += 256) {
        int t = u >> 3, c8 = u & 7;
        short8v v = *(const short8v*)(kvbb + ((size_t)(t0 + t) * 16 + n) * 256 + 128 + dv0 + c8 * 8);
        *(short8v*)(&tile[t][c8 * 8]) = v;
    }
    __syncthreads();
    for (int u = tid; u < 512; u += 256) {
        int dv = u & 63, t8 = u >> 6;
        short8v v;
        #pragma unroll
        for (int e = 0; e < 8; ++e) v[e] = (short)tile[t8 * 8 + e][dv];
        *(short8v*)(Vtc + ((size_t)n * 128 + dv0 + dv) * 2048 + t0 + t8 * 8) = v;
    }
}

// =================== MFMA flash attention (2 blocks/CU, counted vmcnt) ===================
#define QBLK  64
#define KVBLK 64

__global__ __launch_bounds__(256) void attn_mfma(
    const unsigned short* __restrict__ qb,   // [T][16][192] bf16 (scale folded)
    const unsigned short* __restrict__ Kc,   // [16][T][192] bf16
    const unsigned short* __restrict__ Vtc,  // [16][128][T] bf16
    unsigned short* __restrict__ out)        // [T][2048] bf16
{
    __shared__ __align__(16) unsigned short Ks[2][KVBLK * 192];  // 2x24 KB (dbuf)
    __shared__ __align__(16) unsigned short Vt[128 * KVBLK];     // 16 KB
    __shared__ __align__(16) unsigned short Ps[4][16 * KVBLK];   //  8 KB

    // 512 blocks, 2/CU. bid%8 -> XCD; bid and bid+256 co-resident on one CU:
    // same head n, complementary qt (light + heavy) -> balanced makespan 33.
    const int bid  = blockIdx.x;
    const int xcd  = bid & 7;
    const int w    = bid >> 3;            // 0..63
    const int base = w & 31;
    const int n    = xcd * 2 + (base & 1);
    const int qt   = (w >= 32) ? (31 - (base >> 1)) : (base >> 1);

    const int tid = threadIdx.x;
    const int lane = tid & 63, wid = tid >> 6;
    const int lrow = lane & 15;
    const int lkg  = lane >> 4;
    const int q0 = qt * QBLK;

    const unsigned short* Kh = Kc  + (size_t)n * 2048 * 192;
    const unsigned short* Vh = Vtc + (size_t)n * 128 * 2048;

    // ---- hoisted staging offsets (loop-invariant; divisions once) ----
    int koff[6], voff[4];
    #pragma unroll
    for (int p = 0; p < 6; ++p) {
        int u = p * 256 + tid;            // 0..1535
        int row = u / 24, c8 = u % 24;
        koff[p] = row * 192 + ((c8 ^ (row & 7)) << 3);
    }
    #pragma unroll
    for (int p = 0; p < 4; ++p) {
        int u = p * 256 + tid;            // 0..1023
        int dv = u >> 3, c8 = u & 7;
        voff[p] = dv * 2048 + ((c8 ^ (dv & 7)) << 3);
    }

    // ---- Q fragments ----
    short8v qf[6];
    {
        const unsigned short* qrow = qb + ((size_t)(q0 + wid * 16 + lrow) * 16 + n) * 192;
        #pragma unroll
        for (int ds = 0; ds < 6; ++ds)
            qf[ds] = *(const short8v*)(qrow + ds * 32 + lkg * 8);
    }

    f32x4 oacc[8];
    #pragma unroll
    for (int i = 0; i < 8; ++i) oacc[i] = (f32x4)0.f;
    float mrow[4] = {-3e38f, -3e38f, -3e38f, -3e38f};
    float lsum[4] = {0.f, 0.f, 0.f, 0.f};

    const int nt = qt + 1;

    // ---- prologue: issue K[0] (no wait; loop's vmcnt covers it) ----
    #pragma unroll
    for (int p = 0; p < 6; ++p)
        gload16(Kh + koff[p], Ks[0] + (p * 256 + wid * 64) * 8);

    int cur = 0;
    for (int tile = 0; tile < nt; ++tile) {
        const int s0 = tile * KVBLK;

        // ---- issue V[tile] (+4/wave); prev end-barrier protects Vt ----
        #pragma unroll
        for (int p = 0; p < 4; ++p)
            gload16(Vh + s0 + voff[p], Vt + (p * 256 + wid * 64) * 8);
        // ---- issue K[tile+1] (+6/wave) then wait K[tile] landed ----
        if (tile + 1 < nt) {
            #pragma unroll
            for (int p = 0; p < 6; ++p)
                gload16(Kh + (size_t)(s0 + KVBLK) * 192 + koff[p],
                        Ks[cur ^ 1] + (p * 256 + wid * 64) * 8);
            asm volatile("s_waitcnt vmcnt(10)" ::: "memory");  // leaves V[t]+K[t+1]
        } else {
            asm volatile("s_waitcnt vmcnt(4)" ::: "memory");   // leaves V[t]
        }
        __builtin_amdgcn_s_barrier();                          // K[t] visible to all waves

        // ---- S = Q K^T from Ks[cur] ----
        f32x4 sacc[4];
        #pragma unroll
        for (int ct = 0; ct < 4; ++ct) sacc[ct] = (f32x4)0.f;
        __builtin_amdgcn_s_setprio(1);
        #pragma unroll
        for (int ds = 0; ds < 6; ++ds) {
            #pragma unroll
            for (int ct = 0; ct < 4; ++ct) {
                int krow = ct * 16 + lrow;
                int byte = (krow * 384 + ds * 64 + lkg * 16) ^ ((krow & 7) << 4);
                short8v bf = *(const short8v*)((char*)Ks[cur] + byte);
                sacc[ct] = __builtin_amdgcn_mfma_f32_16x16x32_bf16(qf[ds], bf, sacc[ct], 0, 0, 0);
            }
        }
        __builtin_amdgcn_s_setprio(0);

        // ---- causal mask ----
        #pragma unroll
        for (int ct = 0; ct < 4; ++ct) {
            int key = s0 + ct * 16 + lrow;
            #pragma unroll
            for (int jj = 0; jj < 4; ++jj) {
                int gqr = q0 + wid * 16 + lkg * 4 + jj;
                if (key > gqr) sacc[ct][jj] = -3e38f;
            }
        }

        // ---- online softmax ----
        float corr[4];
        #pragma unroll
        for (int jj = 0; jj < 4; ++jj) {
            float tm = fmaxf(fmaxf(sacc[0][jj], sacc[1][jj]), fmaxf(sacc[2][jj], sacc[3][jj]));
            #pragma unroll
            for (int w2 = 1; w2 < 16; w2 <<= 1) tm = fmaxf(tm, __shfl_xor(tm, w2, 16));
            float mn = fmaxf(mrow[jj], tm);
            corr[jj] = __expf(mrow[jj] - mn);
            mrow[jj] = mn;
        }
        float psum[4] = {0.f, 0.f, 0.f, 0.f};
        unsigned short pb[4][4];
        #pragma unroll
        for (int ct = 0; ct < 4; ++ct)
            #pragma unroll
            for (int jj = 0; jj < 4; ++jj) {
                float p = __expf(sacc[ct][jj] - mrow[jj]);
                psum[jj] += p;
                pb[ct][jj] = f2bf(p);
            }
        #pragma unroll
        for (int jj = 0; jj < 4; ++jj) {
            float ps = psum[jj];
            #pragma unroll
            for (int w2 = 1; w2 < 16; w2 <<= 1) ps += __shfl_xor(ps, w2, 16);
            lsum[jj] = lsum[jj] * corr[jj] + ps;
        }
        #pragma unroll
        for (int dt = 0; dt < 8; ++dt)
            #pragma unroll
            for (int jj = 0; jj < 4; ++jj) oacc[dt][jj] *= corr[jj];

        // ---- P -> per-wave LDS (wave-local) ----
        #pragma unroll
        for (int ct = 0; ct < 4; ++ct)
            #pragma unroll
            for (int jj = 0; jj < 4; ++jj) {
                int r = lkg * 4 + jj, c = ct * 16 + lrow;
                int byte = ((r * 64 + c) * 2) ^ ((r & 7) << 4);
                *(unsigned short*)((char*)Ps[wid] + byte) = pb[ct][jj];
            }

        // ---- wait V[tile] landed (K[t+1] stays in flight) ----
        if (tile + 1 < nt) asm volatile("s_waitcnt vmcnt(6)" ::: "memory");
        else               asm volatile("s_waitcnt vmcnt(0)" ::: "memory");
        __builtin_amdgcn_s_barrier();                          // V visible to all waves

        // ---- O += P V ----
        __builtin_amdgcn_s_setprio(1);
        #pragma unroll
        for (int ks = 0; ks < 2; ++ks) {
            int abyte = ((lrow * 64 + ks * 32 + lkg * 8) * 2) ^ ((lrow & 7) << 4);
            short8v af = *(const short8v*)((char*)Ps[wid] + abyte);
            #pragma unroll
            for (int dt = 0; dt < 8; ++dt) {
                int vrow = dt * 16 + lrow;
                int byte = ((vrow * 128 + ks * 64 + lkg * 16)) ^ ((vrow & 7) << 4);
                short8v bf = *(const short8v*)((char*)Vt + byte);
                oacc[dt] = __builtin_amdgcn_mfma_f32_16x16x32_bf16(af, bf, oacc[dt], 0, 0, 0);
            }
        }
        __builtin_amdgcn_s_setprio(0);

        __builtin_amdgcn_s_barrier();   // Vt/Ks[cur] reads done before next-iter writes
        cur ^= 1;
    }

    // ---- epilogue ----
    float inv[4];
    #pragma unroll
    for (int jj = 0; jj < 4; ++jj) inv[jj] = 1.0f / lsum[jj];
    #pragma unroll
    for (int dt = 0; dt < 8; ++dt)
        #pragma unroll
        for (int jj = 0; jj < 4; ++jj) {
            int grow = q0 + wid * 16 + lkg * 4 + jj;
            out[(size_t)grow * 2048 + n * 128 + dt * 16 + lrow] = f2bf(oacc[dt][jj] * inv[jj]);
        }
}

extern "C" void kernel_launch(void* const* d_in, const int* in_sizes, int n_in,
                              void* d_out, int out_size, void* d_ws, size_t ws_size,
                              hipStream_t stream)
{
    const float* x         = (const float*)d_in[0];
    const int*   positions = (const int*)  d_in[1];
    const float* w_q_a     = (const float*)d_in[2];
    const float* q_a_norm  = (const float*)d_in[3];
    const float* w_q_b     = (const float*)d_in[4];
    const float* w_kv_a    = (const float*)d_in[5];
    const float* kv_a_norm = (const float*)d_in[6];
    const float* w_kv_b    = (const float*)d_in[7];
    const float* w_o       = (const float*)d_in[8];
    float* out = (float*)d_out;

    // ---- workspace layout (~85.4 MB) ----
    float* q   = (float*)d_ws;                          // 2048*3072 f32 (later Kc/Vtc)
    float* kv  = q + (size_t)2048 * 3072;               // 2048*576 f32
    unsigned short* kvbb = (unsigned short*)(kv + (size_t)2048 * 576); // 2048*4096 bf16
    float* q_c = (float*)kvbb;                          // alias (2048*1536 f32, dead before kvbb)
    unsigned short* q_cb  = kvbb + (size_t)2048 * 4096; // 2048*1536
    unsigned short* kv_cb = q_cb + (size_t)2048 * 1536; // 2048*512
    unsigned short* xb    = kv_cb + (size_t)2048 * 512; // 2048*2048
    unsigned short* aob   = xb;                         // alias (xb dead before attn)
    unsigned short* qb    = xb + (size_t)2048 * 2048;   // 2048*16*192
    unsigned short* wbuf  = qb + (size_t)2048 * 3072;   // 3072*1536 max
    unsigned short* Kc    = (unsigned short*)q;         // 16*2048*192 (q dead after rope_qb)
    unsigned short* Vtc   = Kc + (size_t)16 * 2048 * 192; // 16*128*2048

    dim3 blk(256);

    // x -> bf16
    conv_bf16<<<(2048 * 2048 / 4 + 255) / 256, blk, 0, stream>>>(x, xb, 2048 * 2048 / 4);

    // G1: q_c = x @ w_q_a   (N=1536, K=2048) fp32 out
    wt_bf16<<<dim3(1536 / 32, 2048 / 32), blk, 0, stream>>>(w_q_a, wbuf, 2048, 1536);
    gemm_bf16<false><<<dim3(1536 / 128, 16), blk, 0, stream>>>(xb, wbuf, q_c, 1536, 2048, 1536);
    rmsnorm_bf16<<<2048, blk, 0, stream>>>(q_c, q_a_norm, q_cb, 1536);

    // G2: q = q_cb @ w_q_b  (N=3072, K=1536) fp32 out; then rope+pack -> qb
    wt_bf16<<<dim3(3072 / 32, 1536 / 32), blk, 0, stream>>>(w_q_b, wbuf, 1536, 3072);
    gemm_bf16<false><<<dim3(3072 / 128, 16), blk, 0, stream>>>(q_cb, wbuf, q, 3072, 1536, 3072);
    rope_qb<<<2048, dim3(192), 0, stream>>>(q, positions, qb);   // q dead after

    // G3: kv = x @ w_kv_a   (N=576, K=2048) fp32 out
    wt_bf16<<<dim3(576 / 32, 2048 / 32), blk, 0, stream>>>(w_kv_a, wbuf, 2048, 576);
    gemm_bf16<false><<<dim3(5, 16), blk, 0, stream>>>(xb, wbuf, kv, 576, 2048, 576);
    kv_fuse<<<2048, blk, 0, stream>>>(kv, kv_a_norm, positions, kv_cb);

    // G4: kvbb = kv_cb @ w_kv_b  (N=4096, K=512) bf16 out
    wt_bf16<<<dim3(4096 / 32, 512 / 32), blk, 0, stream>>>(w_kv_b, wbuf, 512, 4096);
    gemm_bf16<true><<<dim3(4096 / 128, 16), blk, 0, stream>>>(kv_cb, wbuf, kvbb, 4096, 512, 4096);

    // repack K and V^T caches (overwrites q's space)
    repack_k<<<2048, blk, 0, stream>>>(kvbb, kv, Kc);
    repack_vt<<<dim3(32, 32), blk, 0, stream>>>(kvbb, Vtc);

    // attention (512 blocks = 2/CU, complement-paired, counted-vmcnt pipeline)
    attn_mfma<<<512, blk, 0, stream>>>(qb, Kc, Vtc, aob);

    // G5: out = aob @ w_o   (N=2048, K=2048) fp32 out
    wt_bf16<<<dim3(2048 / 32, 2048 / 32), blk, 0, stream>>>(w_o, wbuf, 2048, 2048);
    gemm_bf16<false><<<dim3(2048 / 128, 16), blk, 0, stream>>>(aob, wbuf, out, 2048, 2048, 2048);
}

// Round 10
// 295.631 us; speedup vs baseline: 1.0061x; 1.0061x over previous
//
#include <hip/hip_runtime.h>
#include <hip/hip_bf16.h>
#include <math.h>

#define T_TOK   2048
#define NHEADS  16
#define EPS_    1e-6f
#define THETA_  10000.0f

typedef __attribute__((ext_vector_type(8))) short short8v;
typedef __attribute__((ext_vector_type(4))) float f32x4;

__device__ inline unsigned short f2bf(float f) {
    union { float f; unsigned u; } v; v.f = f;
    unsigned r = v.u + 0x7fffu + ((v.u >> 16) & 1u);
    return (unsigned short)(r >> 16);
}

// async global->LDS, 16B per lane; LDS dest is wave-uniform base + lane*16
__device__ __forceinline__ void gload16(const unsigned short* src, unsigned short* lds) {
    __builtin_amdgcn_global_load_lds(
        (const __attribute__((address_space(1))) unsigned int*)src,
        (__attribute__((address_space(3))) unsigned int*)lds, 16, 0, 0);
}

// ---------------- block-wide reduce (256 threads = 4 waves) ----------------
__device__ inline float block_reduce(float v, bool is_max, float* sred) {
    #pragma unroll
    for (int off = 32; off > 0; off >>= 1) {
        float o = __shfl_down(v, off, 64);
        v = is_max ? fmaxf(v, o) : (v + o);
    }
    int tid = threadIdx.x;
    __syncthreads();
    if ((tid & 63) == 0) sred[tid >> 6] = v;
    __syncthreads();
    float r = sred[0];
    #pragma unroll
    for (int w = 1; w < 4; ++w) r = is_max ? fmaxf(r, sred[w]) : (r + sred[w]);
    return r;
}

// ---------------- fp32 -> bf16 elementwise (n4 = n/4) ----------------
__global__ __launch_bounds__(256) void conv_bf16(const float* __restrict__ in,
    unsigned short* __restrict__ out, int n4)
{
    int i = blockIdx.x * 256 + threadIdx.x;
    if (i >= n4) return;
    float4 v = ((const float4*)in)[i];
    ushort4 o;
    o.x = f2bf(v.x); o.y = f2bf(v.y); o.z = f2bf(v.z); o.w = f2bf(v.w);
    ((ushort4*)out)[i] = o;
}

// ------------- fp32 [R][C] -> bf16 transposed [C][R] -------------
__global__ __launch_bounds__(256) void wt_bf16(const float* __restrict__ W,
    unsigned short* __restrict__ Wt, int R, int C)
{
    __shared__ float tile[32][33];
    int c0 = blockIdx.x * 32, r0 = blockIdx.y * 32;
    int tx = threadIdx.x & 31, ty = threadIdx.x >> 5;  // ty 0..7
    #pragma unroll
    for (int i = 0; i < 4; ++i)
        tile[ty + i * 8][tx] = W[(size_t)(r0 + ty + i * 8) * C + c0 + tx];
    __syncthreads();
    #pragma unroll
    for (int i = 0; i < 4; ++i)
        Wt[(size_t)(c0 + ty + i * 8) * R + r0 + tx] = f2bf(tile[tx][ty + i * 8]);
}

// =============== bf16 MFMA GEMM: C[M,N] = A[M,K] * Bt[N,K]^T ===============
// 128x128 tile, BK=64, 4 waves; global_load_lds staging + double buffer.
template<bool BF16OUT>
__global__ __launch_bounds__(256) void gemm_bf16(
    const unsigned short* __restrict__ A,   // [M][K] bf16
    const unsigned short* __restrict__ Bt,  // [>=gridX*128][K] bf16
    void* __restrict__ Cv, int N, int K, int ldc)
{
    __shared__ __align__(16) unsigned short As[2][128 * 64];
    __shared__ __align__(16) unsigned short Bs[2][128 * 64];
    const int tid = threadIdx.x;
    const int lane = tid & 63, wid = tid >> 6;
    const int wr = wid >> 1, wc = wid & 1;
    const int lrow = lane & 15, lkg = lane >> 4;
    const int r0 = blockIdx.y * 128, c0 = blockIdx.x * 128;

    f32x4 acc[4][4];
    #pragma unroll
    for (int m = 0; m < 4; ++m)
        #pragma unroll
        for (int n = 0; n < 4; ++n) acc[m][n] = (f32x4)0.f;

    // per-pass staging: unit u = p*256+tid -> row r=u>>3, chunk cu=u&7
    // global src is inverse-swizzled; LDS dest linear (wave-uniform base).
    #define STAGE_GEMM(buf, k0)                                                   \
        {   _Pragma("unroll")                                                     \
            for (int p = 0; p < 4; ++p) {                                         \
                int u = p * 256 + tid;                                            \
                int r = u >> 3, cu = u & 7;                                       \
                int dst = (p * 256 + wid * 64) * 8;                               \
                gload16(A  + (size_t)(r0 + r) * K + (k0) + ((cu ^ (r & 7)) << 3), \
                        As[buf] + dst);                                           \
                gload16(Bt + (size_t)(c0 + r) * K + (k0) + ((cu ^ (r & 7)) << 3), \
                        Bs[buf] + dst);                                           \
            }                                                                     \
        }

    STAGE_GEMM(0, 0)
    __syncthreads();

    const int nkt = K >> 6;
    int buf = 0;
    for (int kt = 0; kt < nkt; ++kt) {
        if (kt + 1 < nkt) STAGE_GEMM(buf ^ 1, (kt + 1) << 6)
        #pragma unroll
        for (int ks = 0; ks < 2; ++ks) {
            short8v af[4], bf[4];
            #pragma unroll
            for (int m = 0; m < 4; ++m) {
                int row = wr * 64 + m * 16 + lrow;
                af[m] = *(const short8v*)((char*)As[buf] + row * 128 + (((ks * 4 + lkg) ^ (row & 7)) << 4));
            }
            #pragma unroll
            for (int n = 0; n < 4; ++n) {
                int row = wc * 64 + n * 16 + lrow;
                bf[n] = *(const short8v*)((char*)Bs[buf] + row * 128 + (((ks * 4 + lkg) ^ (row & 7)) << 4));
            }
            __builtin_amdgcn_s_setprio(1);
            #pragma unroll
            for (int m = 0; m < 4; ++m)
                #pragma unroll
                for (int n = 0; n < 4; ++n)
                    acc[m][n] = __builtin_amdgcn_mfma_f32_16x16x32_bf16(af[m], bf[n], acc[m][n], 0, 0, 0);
            __builtin_amdgcn_s_setprio(0);
        }
        __syncthreads();   // drains vmcnt: next tile staged; buf reads done
        buf ^= 1;
    }
    #undef STAGE_GEMM

    // D layout: col = lane&15, row = (lane>>4)*4 + j
    #pragma unroll
    for (int m = 0; m < 4; ++m) {
        int grow = r0 + wr * 64 + m * 16 + lkg * 4;
        #pragma unroll
        for (int n = 0; n < 4; ++n) {
            int gcol = c0 + wc * 64 + n * 16 + lrow;
            if (gcol < N) {
                #pragma unroll
                for (int j = 0; j < 4; ++j) {
                    if (BF16OUT)
                        ((unsigned short*)Cv)[(size_t)(grow + j) * ldc + gcol] = f2bf(acc[m][n][j]);
                    else
                        ((float*)Cv)[(size_t)(grow + j) * ldc + gcol] = acc[m][n][j];
                }
            }
        }
    }
}

// ---------------- RMSNorm rows -> bf16 ----------------
__global__ __launch_bounds__(256) void rmsnorm_bf16(const float* __restrict__ y,
    const float* __restrict__ g, unsigned short* __restrict__ o, int width)
{
    __shared__ float sred[4];
    int row = blockIdx.x;
    const float* p = y + (size_t)row * width;
    float ss = 0.f;
    for (int i = threadIdx.x; i < width; i += 256) { float v = p[i]; ss += v * v; }
    ss = block_reduce(ss, false, sred);
    float sc = rsqrtf(ss / (float)width + EPS_);
    for (int i = threadIdx.x; i < width; i += 256)
        o[(size_t)row * width + i] = f2bf(p[i] * sc * g[i]);
}

// -- kv row: rmsnorm first 512 -> bf16 out ; RoPE cols 512..575 fp32 inplace --
__global__ __launch_bounds__(256) void kv_fuse(float* __restrict__ kv,
    const float* __restrict__ g, const int* __restrict__ positions,
    unsigned short* __restrict__ kvcb)
{
    __shared__ float sred[4];
    int row = blockIdx.x;
    float* p = kv + (size_t)row * 576;
    float ss = 0.f;
    for (int i = threadIdx.x; i < 512; i += 256) { float v = p[i]; ss += v * v; }
    ss = block_reduce(ss, false, sred);
    float sc = rsqrtf(ss / 512.0f + EPS_);
    for (int i = threadIdx.x; i < 512; i += 256)
        kvcb[(size_t)row * 512 + i] = f2bf(p[i] * sc * g[i]);
    if (threadIdx.x < 32) {
        int i = threadIdx.x;
        float pos = (float)positions[row];
        float inv = powf(THETA_, -(float)i / 32.0f);
        float ang = pos * inv;
        float c = cosf(ang), s = sinf(ang);
        float x1 = p[512 + i], x2 = p[544 + i];
        p[512 + i] = x1 * c - x2 * s;
        p[544 + i] = x2 * c + x1 * s;
    }
}

// -------- RoPE + scale + bf16 pack of q: [T][3072] f32 -> [T][16][192] bf16 --------
__global__ __launch_bounds__(192) void rope_qb(const float* __restrict__ q,
    const int* __restrict__ positions, unsigned short* __restrict__ qb)
{
    int t = blockIdx.x, d = threadIdx.x;
    const float scale = 0.07216878364870323f;  // (128+64)^-0.5
    float c = 1.f, s = 0.f;
    if (d >= 128) {
        int i = (d - 128) & 31;
        float pos = (float)positions[t];
        float inv = powf(THETA_, -(float)i / 32.0f);
        float ang = pos * inv;
        c = cosf(ang); s = sinf(ang);
    }
    #pragma unroll 4
    for (int n = 0; n < 16; ++n) {
        const float* p = q + (size_t)t * 3072 + n * 192;
        float v;
        if (d < 128)      v = p[d];
        else if (d < 160) v = p[d] * c - p[d + 32] * s;
        else              v = p[d] * c + p[d - 32] * s;
        qb[((size_t)t * 16 + n) * 192 + d] = f2bf(v * scale);
    }
}

// -------- K cache: [16][T][192] bf16 = k_nope (from kvb bf16) + roped k_pe --------
__global__ __launch_bounds__(256) void repack_k(const unsigned short* __restrict__ kvbb,
    const float* __restrict__ kv, unsigned short* __restrict__ Kc)
{
    int t = blockIdx.x, tid = threadIdx.x;
    int n = tid >> 4;
    int c8 = tid & 15;
    short8v v = *(const short8v*)(kvbb + ((size_t)t * 16 + n) * 256 + c8 * 8);
    *(short8v*)(Kc + ((size_t)n * 2048 + t) * 192 + c8 * 8) = v;
    int i4 = (tid & 15) * 4;
    float4 p = *(const float4*)(kv + (size_t)t * 576 + 512 + i4);
    ushort4 o; o.x = f2bf(p.x); o.y = f2bf(p.y); o.z = f2bf(p.z); o.w = f2bf(p.w);
    *(ushort4*)(Kc + ((size_t)n * 2048 + t) * 192 + 128 + i4) = o;
}

// -------- V^T cache: [16][128][T] bf16, LDS-tiled 64x64 transpose --------
__global__ __launch_bounds__(256) void repack_vt(const unsigned short* __restrict__ kvbb,
    unsigned short* __restrict__ Vtc)
{
    __shared__ unsigned short tile[64][72];
    int t0 = blockIdx.x * 64;
    int n = blockIdx.y >> 1, dv0 = (blockIdx.y & 1) * 64;
    int tid = threadIdx.x;
    for (int u = tid; u < 512; u += 256) {
        int t = u >> 3, c8 = u & 7;
        short8v v = *(const short8v*)(kvbb + ((size_t)(t0 + t) * 16 + n) * 256 + 128 + dv0 + c8 * 8);
        *(short8v*)(&tile[t][c8 * 8]) = v;
    }
    __syncthreads();
    for (int u = tid; u < 512; u += 256) {
        int dv = u & 63, t8 = u >> 6;
        short8v v;
        #pragma unroll
        for (int e = 0; e < 8; ++e) v[e] = (short)tile[t8 * 8 + e][dv];
        *(short8v*)(Vtc + ((size_t)n * 128 + dv0 + dv) * 2048 + t0 + t8 * 8) = v;
    }
}

// ============ MFMA flash attention (48 KB LDS -> 2 blocks/CU) ============
#define QBLK  64
#define KVBLK 64

__global__ __launch_bounds__(256) void attn_mfma(
    const unsigned short* __restrict__ qb,   // [T][16][192] bf16 (scale folded)
    const unsigned short* __restrict__ Kc,   // [16][T][192] bf16
    const unsigned short* __restrict__ Vtc,  // [16][128][T] bf16
    unsigned short* __restrict__ out)        // [T][2048] bf16
{
    __shared__ __align__(16) unsigned short Ks[KVBLK * 192];   // 24 KB
    __shared__ __align__(16) unsigned short Vt[128 * KVBLK];   // 16 KB
    __shared__ __align__(16) unsigned short Ps[4][16 * KVBLK]; //  8 KB  (48 total)

    // 512 blocks, 2/CU target. bid%8 -> XCD; bid and bid+256 co-resident:
    // same head n, complementary qt (light + heavy).
    const int bid  = blockIdx.x;
    const int xcd  = bid & 7;
    const int w    = bid >> 3;            // 0..63
    const int base = w & 31;
    const int n    = xcd * 2 + (base & 1);
    const int qt   = (w >= 32) ? (31 - (base >> 1)) : (base >> 1);

    const int tid = threadIdx.x;
    const int lane = tid & 63, wid = tid >> 6;
    const int lrow = lane & 15;
    const int lkg  = lane >> 4;
    const int q0 = qt * QBLK;

    const unsigned short* Kh = Kc  + (size_t)n * 2048 * 192;
    const unsigned short* Vh = Vtc + (size_t)n * 128 * 2048;

    // ---- hoisted staging offsets (loop-invariant) ----
    int koff[6], voff[4];
    #pragma unroll
    for (int p = 0; p < 6; ++p) {
        int u = p * 256 + tid;            // 0..1535
        int row = u / 24, c8 = u % 24;
        koff[p] = row * 192 + ((c8 ^ (row & 7)) << 3);
    }
    #pragma unroll
    for (int p = 0; p < 4; ++p) {
        int u = p * 256 + tid;            // 0..1023
        int dv = u >> 3, c8 = u & 7;
        voff[p] = dv * 2048 + ((c8 ^ (dv & 7)) << 3);
    }

    // ---- Q fragments ----
    short8v qf[6];
    {
        const unsigned short* qrow = qb + ((size_t)(q0 + wid * 16 + lrow) * 16 + n) * 192;
        #pragma unroll
        for (int ds = 0; ds < 6; ++ds)
            qf[ds] = *(const short8v*)(qrow + ds * 32 + lkg * 8);
    }

    f32x4 oacc[8];
    #pragma unroll
    for (int i = 0; i < 8; ++i) oacc[i] = (f32x4)0.f;
    float mrow[4] = {-3e38f, -3e38f, -3e38f, -3e38f};
    float lsum[4] = {0.f, 0.f, 0.f, 0.f};

    const int nt = qt + 1;

    // ---- prologue: issue K[0] then V[0] (10 outstanding/wave) ----
    #pragma unroll
    for (int p = 0; p < 6; ++p)
        gload16(Kh + koff[p], Ks + (p * 256 + wid * 64) * 8);
    #pragma unroll
    for (int p = 0; p < 4; ++p)
        gload16(Vh + voff[p], Vt + (p * 256 + wid * 64) * 8);

    for (int tile = 0; tile < nt; ++tile) {
        const int s0 = tile * KVBLK;

        // ---- K[t] landed (V may still be in flight) ----
        asm volatile("s_waitcnt vmcnt(4)" ::: "memory");
        __builtin_amdgcn_s_barrier();

        // ---- S = Q K^T ----
        f32x4 sacc[4];
        #pragma unroll
        for (int ct = 0; ct < 4; ++ct) sacc[ct] = (f32x4)0.f;
        __builtin_amdgcn_s_setprio(1);
        #pragma unroll
        for (int ds = 0; ds < 6; ++ds) {
            #pragma unroll
            for (int ct = 0; ct < 4; ++ct) {
                int krow = ct * 16 + lrow;
                int byte = (krow * 384 + ds * 64 + lkg * 16) ^ ((krow & 7) << 4);
                short8v bf = *(const short8v*)((char*)Ks + byte);
                sacc[ct] = __builtin_amdgcn_mfma_f32_16x16x32_bf16(qf[ds], bf, sacc[ct], 0, 0, 0);
            }
        }
        __builtin_amdgcn_s_setprio(0);

        // ---- causal mask ----
        #pragma unroll
        for (int ct = 0; ct < 4; ++ct) {
            int key = s0 + ct * 16 + lrow;
            #pragma unroll
            for (int jj = 0; jj < 4; ++jj) {
                int gqr = q0 + wid * 16 + lkg * 4 + jj;
                if (key > gqr) sacc[ct][jj] = -3e38f;
            }
        }

        // ---- online softmax ----
        float corr[4];
        #pragma unroll
        for (int jj = 0; jj < 4; ++jj) {
            float tm = fmaxf(fmaxf(sacc[0][jj], sacc[1][jj]), fmaxf(sacc[2][jj], sacc[3][jj]));
            #pragma unroll
            for (int w2 = 1; w2 < 16; w2 <<= 1) tm = fmaxf(tm, __shfl_xor(tm, w2, 16));
            float mn = fmaxf(mrow[jj], tm);
            corr[jj] = __expf(mrow[jj] - mn);
            mrow[jj] = mn;
        }
        float psum[4] = {0.f, 0.f, 0.f, 0.f};
        unsigned short pb[4][4];
        #pragma unroll
        for (int ct = 0; ct < 4; ++ct)
            #pragma unroll
            for (int jj = 0; jj < 4; ++jj) {
                float p = __expf(sacc[ct][jj] - mrow[jj]);
                psum[jj] += p;
                pb[ct][jj] = f2bf(p);
            }
        #pragma unroll
        for (int jj = 0; jj < 4; ++jj) {
            float ps = psum[jj];
            #pragma unroll
            for (int w2 = 1; w2 < 16; w2 <<= 1) ps += __shfl_xor(ps, w2, 16);
            lsum[jj] = lsum[jj] * corr[jj] + ps;
        }
        #pragma unroll
        for (int dt = 0; dt < 8; ++dt)
            #pragma unroll
            for (int jj = 0; jj < 4; ++jj) oacc[dt][jj] *= corr[jj];

        // ---- P -> per-wave LDS (wave-local) ----
        #pragma unroll
        for (int ct = 0; ct < 4; ++ct)
            #pragma unroll
            for (int jj = 0; jj < 4; ++jj) {
                int r = lkg * 4 + jj, c = ct * 16 + lrow;
                int byte = ((r * 64 + c) * 2) ^ ((r & 7) << 4);
                *(unsigned short*)((char*)Ps[wid] + byte) = pb[ct][jj];
            }

        // ---- V[t] landed ----
        asm volatile("s_waitcnt vmcnt(0)" ::: "memory");
        __builtin_amdgcn_s_barrier();

        // ---- O += P V ----
        __builtin_amdgcn_s_setprio(1);
        #pragma unroll
        for (int ks = 0; ks < 2; ++ks) {
            int abyte = ((lrow * 64 + ks * 32 + lkg * 8) * 2) ^ ((lrow & 7) << 4);
            short8v af = *(const short8v*)((char*)Ps[wid] + abyte);
            #pragma unroll
            for (int dt = 0; dt < 8; ++dt) {
                int vrow = dt * 16 + lrow;
                int byte = ((vrow * 128 + ks * 64 + lkg * 16)) ^ ((vrow & 7) << 4);
                short8v bf = *(const short8v*)((char*)Vt + byte);
                oacc[dt] = __builtin_amdgcn_mfma_f32_16x16x32_bf16(af, bf, oacc[dt], 0, 0, 0);
            }
        }
        __builtin_amdgcn_s_setprio(0);

        // ---- all reads done -> safe to restage ----
        __builtin_amdgcn_s_barrier();
        if (tile + 1 < nt) {
            const int s1 = s0 + KVBLK;
            #pragma unroll
            for (int p = 0; p < 6; ++p)
                gload16(Kh + (size_t)s1 * 192 + koff[p], Ks + (p * 256 + wid * 64) * 8);
            #pragma unroll
            for (int p = 0; p < 4; ++p)
                gload16(Vh + s1 + voff[p], Vt + (p * 256 + wid * 64) * 8);
        }
    }

    // ---- epilogue ----
    float inv[4];
    #pragma unroll
    for (int jj = 0; jj < 4; ++jj) inv[jj] = 1.0f / lsum[jj];
    #pragma unroll
    for (int dt = 0; dt < 8; ++dt)
        #pragma unroll
        for (int jj = 0; jj < 4; ++jj) {
            int grow = q0 + wid * 16 + lkg * 4 + jj;
            out[(size_t)grow * 2048 + n * 128 + dt * 16 + lrow] = f2bf(oacc[dt][jj] * inv[jj]);
        }
}

extern "C" void kernel_launch(void* const* d_in, const int* in_sizes, int n_in,
                              void* d_out, int out_size, void* d_ws, size_t ws_size,
                              hipStream_t stream)
{
    const float* x         = (const float*)d_in[0];
    const int*   positions = (const int*)  d_in[1];
    const float* w_q_a     = (const float*)d_in[2];
    const float* q_a_norm  = (const float*)d_in[3];
    const float* w_q_b     = (const float*)d_in[4];
    const float* w_kv_a    = (const float*)d_in[5];
    const float* kv_a_norm = (const float*)d_in[6];
    const float* w_kv_b    = (const float*)d_in[7];
    const float* w_o       = (const float*)d_in[8];
    float* out = (float*)d_out;

    // ---- workspace layout (~85.4 MB) ----
    float* q   = (float*)d_ws;                          // 2048*3072 f32 (later Kc/Vtc)
    float* kv  = q + (size_t)2048 * 3072;               // 2048*576 f32
    unsigned short* kvbb = (unsigned short*)(kv + (size_t)2048 * 576); // 2048*4096 bf16
    float* q_c = (float*)kvbb;                          // alias (2048*1536 f32, dead before kvbb)
    unsigned short* q_cb  = kvbb + (size_t)2048 * 4096; // 2048*1536
    unsigned short* kv_cb = q_cb + (size_t)2048 * 1536; // 2048*512
    unsigned short* xb    = kv_cb + (size_t)2048 * 512; // 2048*2048
    unsigned short* aob   = xb;                         // alias (xb dead before attn)
    unsigned short* qb    = xb + (size_t)2048 * 2048;   // 2048*16*192
    unsigned short* wbuf  = qb + (size_t)2048 * 3072;   // 3072*1536 max
    unsigned short* Kc    = (unsigned short*)q;         // 16*2048*192 (q dead after rope_qb)
    unsigned short* Vtc   = Kc + (size_t)16 * 2048 * 192; // 16*128*2048

    dim3 blk(256);

    // x -> bf16
    conv_bf16<<<(2048 * 2048 / 4 + 255) / 256, blk, 0, stream>>>(x, xb, 2048 * 2048 / 4);

    // G1: q_c = x @ w_q_a   (N=1536, K=2048) fp32 out
    wt_bf16<<<dim3(1536 / 32, 2048 / 32), blk, 0, stream>>>(w_q_a, wbuf, 2048, 1536);
    gemm_bf16<false><<<dim3(1536 / 128, 16), blk, 0, stream>>>(xb, wbuf, q_c, 1536, 2048, 1536);
    rmsnorm_bf16<<<2048, blk, 0, stream>>>(q_c, q_a_norm, q_cb, 1536);

    // G2: q = q_cb @ w_q_b  (N=3072, K=1536) fp32 out; then rope+pack -> qb
    wt_bf16<<<dim3(3072 / 32, 1536 / 32), blk, 0, stream>>>(w_q_b, wbuf, 1536, 3072);
    gemm_bf16<false><<<dim3(3072 / 128, 16), blk, 0, stream>>>(q_cb, wbuf, q, 3072, 1536, 3072);
    rope_qb<<<2048, dim3(192), 0, stream>>>(q, positions, qb);   // q dead after

    // G3: kv = x @ w_kv_a   (N=576, K=2048) fp32 out
    wt_bf16<<<dim3(576 / 32, 2048 / 32), blk, 0, stream>>>(w_kv_a, wbuf, 2048, 576);
    gemm_bf16<false><<<dim3(5, 16), blk, 0, stream>>>(xb, wbuf, kv, 576, 2048, 576);
    kv_fuse<<<2048, blk, 0, stream>>>(kv, kv_a_norm, positions, kv_cb);

    // G4: kvbb = kv_cb @ w_kv_b  (N=4096, K=512) bf16 out
    wt_bf16<<<dim3(4096 / 32, 512 / 32), blk, 0, stream>>>(w_kv_b, wbuf, 512, 4096);
    gemm_bf16<true><<<dim3(4096 / 128, 16), blk, 0, stream>>>(kv_cb, wbuf, kvbb, 4096, 512, 4096);

    // repack K and V^T caches (overwrites q's space)
    repack_k<<<2048, blk, 0, stream>>>(kvbb, kv, Kc);
    repack_vt<<<dim3(32, 32), blk, 0, stream>>>(kvbb, Vtc);

    // attention (512 blocks, 48 KB LDS -> 2 blocks/CU, split-wait schedule)
    attn_mfma<<<512, blk, 0, stream>>>(qb, Kc, Vtc, aob);

    // G5: out = aob @ w_o   (N=2048, K=2048) fp32 out
    wt_bf16<<<dim3(2048 / 32, 2048 / 32), blk, 0, stream>>>(w_o, wbuf, 2048, 2048);
    gemm_bf16<false><<<dim3(2048 / 128, 16), blk, 0, stream>>>(aob, wbuf, out, 2048, 2048, 2048);
}

// Round 11
// 283.752 us; speedup vs baseline: 1.0482x; 1.0419x over previous
//
#include <hip/hip_runtime.h>
#include <hip/hip_bf16.h>
#include <math.h>

#define T_TOK   2048
#define NHEADS  16
#define EPS_    1e-6f
#define THETA_  10000.0f

typedef __attribute__((ext_vector_type(8))) short short8v;
typedef __attribute__((ext_vector_type(4))) float f32x4;

__device__ inline unsigned short f2bf(float f) {
    union { float f; unsigned u; } v; v.f = f;
    unsigned r = v.u + 0x7fffu + ((v.u >> 16) & 1u);
    return (unsigned short)(r >> 16);
}

// async global->LDS, 16B per lane; LDS dest is wave-uniform base + lane*16
__device__ __forceinline__ void gload16(const unsigned short* src, unsigned short* lds) {
    __builtin_amdgcn_global_load_lds(
        (const __attribute__((address_space(1))) unsigned int*)src,
        (__attribute__((address_space(3))) unsigned int*)lds, 16, 0, 0);
}

// ---------------- block-wide reduce (256 threads = 4 waves) ----------------
__device__ inline float block_reduce(float v, bool is_max, float* sred) {
    #pragma unroll
    for (int off = 32; off > 0; off >>= 1) {
        float o = __shfl_down(v, off, 64);
        v = is_max ? fmaxf(v, o) : (v + o);
    }
    int tid = threadIdx.x;
    __syncthreads();
    if ((tid & 63) == 0) sred[tid >> 6] = v;
    __syncthreads();
    float r = sred[0];
    #pragma unroll
    for (int w = 1; w < 4; ++w) r = is_max ? fmaxf(r, sred[w]) : (r + sred[w]);
    return r;
}

// ---------------- fp32 -> bf16 elementwise (n4 = n/4) ----------------
__global__ __launch_bounds__(256) void conv_bf16(const float* __restrict__ in,
    unsigned short* __restrict__ out, int n4)
{
    int i = blockIdx.x * 256 + threadIdx.x;
    if (i >= n4) return;
    float4 v = ((const float4*)in)[i];
    ushort4 o;
    o.x = f2bf(v.x); o.y = f2bf(v.y); o.z = f2bf(v.z); o.w = f2bf(v.w);
    ((ushort4*)out)[i] = o;
}

// ------------- fp32 [R][C] -> bf16 transposed [C][R] -------------
__global__ __launch_bounds__(256) void wt_bf16(const float* __restrict__ W,
    unsigned short* __restrict__ Wt, int R, int C)
{
    __shared__ float tile[32][33];
    int c0 = blockIdx.x * 32, r0 = blockIdx.y * 32;
    int tx = threadIdx.x & 31, ty = threadIdx.x >> 5;  // ty 0..7
    #pragma unroll
    for (int i = 0; i < 4; ++i)
        tile[ty + i * 8][tx] = W[(size_t)(r0 + ty + i * 8) * C + c0 + tx];
    __syncthreads();
    #pragma unroll
    for (int i = 0; i < 4; ++i)
        Wt[(size_t)(c0 + ty + i * 8) * R + r0 + tx] = f2bf(tile[tx][ty + i * 8]);
}

// =============== bf16 MFMA GEMM: C[M,N] = A[M,K] * Bt[N,K]^T ===============
// 128x128 tile, BK=64, 4 waves; m97 single-buffer structure (32 KB LDS).
template<bool BF16OUT>
__global__ __launch_bounds__(256) void gemm_bf16(
    const unsigned short* __restrict__ A,   // [M][K] bf16
    const unsigned short* __restrict__ Bt,  // [>=gridX*128][K] bf16
    void* __restrict__ Cv, int N, int K, int ldc)
{
    __shared__ __align__(16) unsigned short As[128 * 64];
    __shared__ __align__(16) unsigned short Bs[128 * 64];
    const int tid = threadIdx.x;
    const int lane = tid & 63, wid = tid >> 6;
    const int wr = wid >> 1, wc = wid & 1;
    const int lrow = lane & 15, lkg = lane >> 4;
    const int r0 = blockIdx.y * 128, c0 = blockIdx.x * 128;

    f32x4 acc[4][4];
    #pragma unroll
    for (int m = 0; m < 4; ++m)
        #pragma unroll
        for (int n = 0; n < 4; ++n) acc[m][n] = (f32x4)0.f;

    const int nkt = K >> 6;
    for (int kt = 0; kt < nkt; ++kt) {
        const int k0 = kt << 6;
        if (kt) __syncthreads();          // prev compute done before restage
        #pragma unroll
        for (int p = 0; p < 4; ++p) {
            int u = p * 256 + tid;        // 16B unit 0..1023
            int r = u >> 3, cu = u & 7;
            int dst = (p * 256 + wid * 64) * 8;
            gload16(A  + (size_t)(r0 + r) * K + k0 + ((cu ^ (r & 7)) << 3), As + dst);
            gload16(Bt + (size_t)(c0 + r) * K + k0 + ((cu ^ (r & 7)) << 3), Bs + dst);
        }
        __syncthreads();                  // drains vmcnt: tile staged
        #pragma unroll
        for (int ks = 0; ks < 2; ++ks) {
            short8v af[4], bf[4];
            #pragma unroll
            for (int m = 0; m < 4; ++m) {
                int row = wr * 64 + m * 16 + lrow;
                af[m] = *(const short8v*)((char*)As + row * 128 + (((ks * 4 + lkg) ^ (row & 7)) << 4));
            }
            #pragma unroll
            for (int n = 0; n < 4; ++n) {
                int row = wc * 64 + n * 16 + lrow;
                bf[n] = *(const short8v*)((char*)Bs + row * 128 + (((ks * 4 + lkg) ^ (row & 7)) << 4));
            }
            #pragma unroll
            for (int m = 0; m < 4; ++m)
                #pragma unroll
                for (int n = 0; n < 4; ++n)
                    acc[m][n] = __builtin_amdgcn_mfma_f32_16x16x32_bf16(af[m], bf[n], acc[m][n], 0, 0, 0);
        }
    }

    // D layout: col = lane&15, row = (lane>>4)*4 + j
    #pragma unroll
    for (int m = 0; m < 4; ++m) {
        int grow = r0 + wr * 64 + m * 16 + lkg * 4;
        #pragma unroll
        for (int n = 0; n < 4; ++n) {
            int gcol = c0 + wc * 64 + n * 16 + lrow;
            if (gcol < N) {
                #pragma unroll
                for (int j = 0; j < 4; ++j) {
                    if (BF16OUT)
                        ((unsigned short*)Cv)[(size_t)(grow + j) * ldc + gcol] = f2bf(acc[m][n][j]);
                    else
                        ((float*)Cv)[(size_t)(grow + j) * ldc + gcol] = acc[m][n][j];
                }
            }
        }
    }
}

// ---------------- RMSNorm rows -> bf16 ----------------
__global__ __launch_bounds__(256) void rmsnorm_bf16(const float* __restrict__ y,
    const float* __restrict__ g, unsigned short* __restrict__ o, int width)
{
    __shared__ float sred[4];
    int row = blockIdx.x;
    const float* p = y + (size_t)row * width;
    float ss = 0.f;
    for (int i = threadIdx.x; i < width; i += 256) { float v = p[i]; ss += v * v; }
    ss = block_reduce(ss, false, sred);
    float sc = rsqrtf(ss / (float)width + EPS_);
    for (int i = threadIdx.x; i < width; i += 256)
        o[(size_t)row * width + i] = f2bf(p[i] * sc * g[i]);
}

// -- kv row: rmsnorm first 512 -> bf16 out ; RoPE cols 512..575 fp32 inplace --
__global__ __launch_bounds__(256) void kv_fuse(float* __restrict__ kv,
    const float* __restrict__ g, const int* __restrict__ positions,
    unsigned short* __restrict__ kvcb)
{
    __shared__ float sred[4];
    int row = blockIdx.x;
    float* p = kv + (size_t)row * 576;
    float ss = 0.f;
    for (int i = threadIdx.x; i < 512; i += 256) { float v = p[i]; ss += v * v; }
    ss = block_reduce(ss, false, sred);
    float sc = rsqrtf(ss / 512.0f + EPS_);
    for (int i = threadIdx.x; i < 512; i += 256)
        kvcb[(size_t)row * 512 + i] = f2bf(p[i] * sc * g[i]);
    if (threadIdx.x < 32) {
        int i = threadIdx.x;
        float pos = (float)positions[row];
        float inv = powf(THETA_, -(float)i / 32.0f);
        float ang = pos * inv;
        float c = cosf(ang), s = sinf(ang);
        float x1 = p[512 + i], x2 = p[544 + i];
        p[512 + i] = x1 * c - x2 * s;
        p[544 + i] = x2 * c + x1 * s;
    }
}

// -------- RoPE + scale + bf16 pack of q: [T][3072] f32 -> [T][16][192] bf16 --------
__global__ __launch_bounds__(192) void rope_qb(const float* __restrict__ q,
    const int* __restrict__ positions, unsigned short* __restrict__ qb)
{
    int t = blockIdx.x, d = threadIdx.x;
    const float scale = 0.07216878364870323f;  // (128+64)^-0.5
    float c = 1.f, s = 0.f;
    if (d >= 128) {
        int i = (d - 128) & 31;
        float pos = (float)positions[t];
        float inv = powf(THETA_, -(float)i / 32.0f);
        float ang = pos * inv;
        c = cosf(ang); s = sinf(ang);
    }
    #pragma unroll 4
    for (int n = 0; n < 16; ++n) {
        const float* p = q + (size_t)t * 3072 + n * 192;
        float v;
        if (d < 128)      v = p[d];
        else if (d < 160) v = p[d] * c - p[d + 32] * s;
        else              v = p[d] * c + p[d - 32] * s;
        qb[((size_t)t * 16 + n) * 192 + d] = f2bf(v * scale);
    }
}

// -------- K cache: [16][T][192] bf16 = k_nope (from kvb bf16) + roped k_pe --------
__global__ __launch_bounds__(256) void repack_k(const unsigned short* __restrict__ kvbb,
    const float* __restrict__ kv, unsigned short* __restrict__ Kc)
{
    int t = blockIdx.x, tid = threadIdx.x;
    int n = tid >> 4;
    int c8 = tid & 15;
    short8v v = *(const short8v*)(kvbb + ((size_t)t * 16 + n) * 256 + c8 * 8);
    *(short8v*)(Kc + ((size_t)n * 2048 + t) * 192 + c8 * 8) = v;
    int i4 = (tid & 15) * 4;
    float4 p = *(const float4*)(kv + (size_t)t * 576 + 512 + i4);
    ushort4 o; o.x = f2bf(p.x); o.y = f2bf(p.y); o.z = f2bf(p.z); o.w = f2bf(p.w);
    *(ushort4*)(Kc + ((size_t)n * 2048 + t) * 192 + 128 + i4) = o;
}

// -------- V^T cache: [16][128][T] bf16, LDS-tiled 64x64 transpose --------
__global__ __launch_bounds__(256) void repack_vt(const unsigned short* __restrict__ kvbb,
    unsigned short* __restrict__ Vtc)
{
    __shared__ unsigned short tile[64][72];
    int t0 = blockIdx.x * 64;
    int n = blockIdx.y >> 1, dv0 = (blockIdx.y & 1) * 64;
    int tid = threadIdx.x;
    for (int u = tid; u < 512; u += 256) {
        int t = u >> 3, c8 = u & 7;
        short8v v = *(const short8v*)(kvbb + ((size_t)(t0 + t) * 16 + n) * 256 + 128 + dv0 + c8 * 8);
        *(short8v*)(&tile[t][c8 * 8]) = v;
    }
    __syncthreads();
    for (int u = tid; u < 512; u += 256) {
        int dv = u & 63, t8 = u >> 6;
        short8v v;
        #pragma unroll
        for (int e = 0; e < 8; ++e) v[e] = (short)tile[t8 * 8 + e][dv];
        *(short8v*)(Vtc + ((size_t)n * 128 + dv0 + dv) * 2048 + t0 + t8 * 8) = v;
    }
}

// ======== MFMA flash attention, KV-split jobs (partials to scratch) ========
#define QBLK  64
#define KVBLK 64
#define NCH   3

__global__ __launch_bounds__(256) void attn_part(
    const unsigned short* __restrict__ qb,    // [T][16][192] bf16 (scale folded)
    const unsigned short* __restrict__ Kc,    // [16][T][192] bf16
    const unsigned short* __restrict__ Vtc,   // [16][128][T] bf16
    unsigned short* __restrict__ Opart,       // [1536][64][128] bf16 unnormalized
    float2* __restrict__ Ml)                  // [1536][64] (m, l)
{
    __shared__ __align__(16) unsigned short Ks[KVBLK * 192];   // 24 KB
    __shared__ __align__(16) unsigned short Vt[128 * KVBLK];   // 16 KB
    __shared__ __align__(16) unsigned short Ps[4][16 * KVBLK]; //  8 KB (48 total)

    // job map: xcd = bid&7 (2 heads/XCD), heavy qt first within head
    const int bid = blockIdx.x;               // 0..1535
    const int xcd = bid & 7;
    const int j   = bid >> 3;                 // 0..191
    const int n   = xcd * 2 + (j >= 96);
    const int jj  = (j >= 96) ? j - 96 : j;   // 0..95
    const int qt  = 31 - (jj / NCH);
    const int ch  = jj % NCH;

    const int nt  = qt + 1;
    const int csz = (nt + NCH - 1) / NCH;
    const int tstart = ch * csz;
    if (tstart >= nt) return;                 // empty chunk
    const int tend = min(tstart + csz, nt);

    const int tid = threadIdx.x;
    const int lane = tid & 63, wid = tid >> 6;
    const int lrow = lane & 15;
    const int lkg  = lane >> 4;
    const int q0 = qt * QBLK;
    const int pidx = ((n * 32 + qt) * NCH + ch);

    const unsigned short* Kh = Kc  + (size_t)n * 2048 * 192;
    const unsigned short* Vh = Vtc + (size_t)n * 128 * 2048;

    // ---- hoisted staging offsets ----
    int koff[6], voff[4];
    #pragma unroll
    for (int p = 0; p < 6; ++p) {
        int u = p * 256 + tid;
        int row = u / 24, c8 = u % 24;
        koff[p] = row * 192 + ((c8 ^ (row & 7)) << 3);
    }
    #pragma unroll
    for (int p = 0; p < 4; ++p) {
        int u = p * 256 + tid;
        int dv = u >> 3, c8 = u & 7;
        voff[p] = dv * 2048 + ((c8 ^ (dv & 7)) << 3);
    }

    // ---- Q fragments ----
    short8v qf[6];
    {
        const unsigned short* qrow = qb + ((size_t)(q0 + wid * 16 + lrow) * 16 + n) * 192;
        #pragma unroll
        for (int ds = 0; ds < 6; ++ds)
            qf[ds] = *(const short8v*)(qrow + ds * 32 + lkg * 8);
    }

    f32x4 oacc[8];
    #pragma unroll
    for (int i = 0; i < 8; ++i) oacc[i] = (f32x4)0.f;
    float mrow[4] = {-3e38f, -3e38f, -3e38f, -3e38f};
    float lsum[4] = {0.f, 0.f, 0.f, 0.f};

    // ---- prologue: issue K[tstart], V[tstart] ----
    #pragma unroll
    for (int p = 0; p < 6; ++p)
        gload16(Kh + (size_t)tstart * KVBLK * 192 + koff[p], Ks + (p * 256 + wid * 64) * 8);
    #pragma unroll
    for (int p = 0; p < 4; ++p)
        gload16(Vh + tstart * KVBLK + voff[p], Vt + (p * 256 + wid * 64) * 8);

    for (int tile = tstart; tile < tend; ++tile) {
        const int s0 = tile * KVBLK;

        asm volatile("s_waitcnt vmcnt(4)" ::: "memory");   // K landed
        __builtin_amdgcn_s_barrier();

        // ---- S = Q K^T ----
        f32x4 sacc[4];
        #pragma unroll
        for (int ct = 0; ct < 4; ++ct) sacc[ct] = (f32x4)0.f;
        __builtin_amdgcn_s_setprio(1);
        #pragma unroll
        for (int ds = 0; ds < 6; ++ds) {
            #pragma unroll
            for (int ct = 0; ct < 4; ++ct) {
                int krow = ct * 16 + lrow;
                int byte = (krow * 384 + ds * 64 + lkg * 16) ^ ((krow & 7) << 4);
                short8v bf = *(const short8v*)((char*)Ks + byte);
                sacc[ct] = __builtin_amdgcn_mfma_f32_16x16x32_bf16(qf[ds], bf, sacc[ct], 0, 0, 0);
            }
        }
        __builtin_amdgcn_s_setprio(0);

        // ---- causal mask ----
        #pragma unroll
        for (int ct = 0; ct < 4; ++ct) {
            int key = s0 + ct * 16 + lrow;
            #pragma unroll
            for (int jq = 0; jq < 4; ++jq) {
                int gqr = q0 + wid * 16 + lkg * 4 + jq;
                if (key > gqr) sacc[ct][jq] = -3e38f;
            }
        }

        // ---- online softmax (guard: all-masked rows must give p=0) ----
        float corr[4];
        #pragma unroll
        for (int jq = 0; jq < 4; ++jq) {
            float tm = fmaxf(fmaxf(sacc[0][jq], sacc[1][jq]), fmaxf(sacc[2][jq], sacc[3][jq]));
            #pragma unroll
            for (int w2 = 1; w2 < 16; w2 <<= 1) tm = fmaxf(tm, __shfl_xor(tm, w2, 16));
            float mn = fmaxf(mrow[jq], tm);
            corr[jq] = __expf(mrow[jq] - mn);
            mrow[jq] = mn;
        }
        float psum[4] = {0.f, 0.f, 0.f, 0.f};
        unsigned short pb[4][4];
        #pragma unroll
        for (int ct = 0; ct < 4; ++ct)
            #pragma unroll
            for (int jq = 0; jq < 4; ++jq) {
                float sv = sacc[ct][jq];
                float p = (sv > -1e37f) ? __expf(sv - mrow[jq]) : 0.f;
                psum[jq] += p;
                pb[ct][jq] = f2bf(p);
            }
        #pragma unroll
        for (int jq = 0; jq < 4; ++jq) {
            float ps = psum[jq];
            #pragma unroll
            for (int w2 = 1; w2 < 16; w2 <<= 1) ps += __shfl_xor(ps, w2, 16);
            lsum[jq] = lsum[jq] * corr[jq] + ps;
        }
        #pragma unroll
        for (int dt = 0; dt < 8; ++dt)
            #pragma unroll
            for (int jq = 0; jq < 4; ++jq) oacc[dt][jq] *= corr[jq];

        // ---- P -> per-wave LDS ----
        #pragma unroll
        for (int ct = 0; ct < 4; ++ct)
            #pragma unroll
            for (int jq = 0; jq < 4; ++jq) {
                int r = lkg * 4 + jq, c = ct * 16 + lrow;
                int byte = ((r * 64 + c) * 2) ^ ((r & 7) << 4);
                *(unsigned short*)((char*)Ps[wid] + byte) = pb[ct][jq];
            }

        asm volatile("s_waitcnt vmcnt(0)" ::: "memory");   // V landed
        __builtin_amdgcn_s_barrier();

        // ---- O += P V ----
        __builtin_amdgcn_s_setprio(1);
        #pragma unroll
        for (int ks = 0; ks < 2; ++ks) {
            int abyte = ((lrow * 64 + ks * 32 + lkg * 8) * 2) ^ ((lrow & 7) << 4);
            short8v af = *(const short8v*)((char*)Ps[wid] + abyte);
            #pragma unroll
            for (int dt = 0; dt < 8; ++dt) {
                int vrow = dt * 16 + lrow;
                int byte = ((vrow * 128 + ks * 64 + lkg * 16)) ^ ((vrow & 7) << 4);
                short8v bf = *(const short8v*)((char*)Vt + byte);
                oacc[dt] = __builtin_amdgcn_mfma_f32_16x16x32_bf16(af, bf, oacc[dt], 0, 0, 0);
            }
        }
        __builtin_amdgcn_s_setprio(0);

        __builtin_amdgcn_s_barrier();      // reads done -> safe to restage
        if (tile + 1 < tend) {
            const int s1 = s0 + KVBLK;
            #pragma unroll
            for (int p = 0; p < 6; ++p)
                gload16(Kh + (size_t)s1 * 192 + koff[p], Ks + (p * 256 + wid * 64) * 8);
            #pragma unroll
            for (int p = 0; p < 4; ++p)
                gload16(Vh + s1 + voff[p], Vt + (p * 256 + wid * 64) * 8);
        }
    }

    // ---- write partials (unnormalized O bf16, m/l fp32) ----
    #pragma unroll
    for (int dt = 0; dt < 8; ++dt)
        #pragma unroll
        for (int jq = 0; jq < 4; ++jq) {
            int row = wid * 16 + lkg * 4 + jq;
            Opart[(size_t)pidx * 8192 + row * 128 + dt * 16 + lrow] = f2bf(oacc[dt][jq]);
        }
    if (lrow == 0) {
        #pragma unroll
        for (int jq = 0; jq < 4; ++jq) {
            int row = wid * 16 + lkg * 4 + jq;
            Ml[(size_t)pidx * 64 + row] = make_float2(mrow[jq], lsum[jq]);
        }
    }
}

// -------- combine <=3 partials per (head, qtile) -> bf16 attention out --------
__global__ __launch_bounds__(256) void attn_combine(
    const unsigned short* __restrict__ Opart, const float2* __restrict__ Ml,
    unsigned short* __restrict__ aob)
{
    const int bid = blockIdx.x;               // 512 = head*32 + qt
    const int head = bid >> 5, qt = bid & 31;
    const int nt = qt + 1, csz = (nt + NCH - 1) / NCH;
    const int nch = (nt + csz - 1) / csz;
    const int tid = threadIdx.x;
    const int r = tid >> 2, qc = tid & 3;     // row 0..63, col-quarter
    const int base = (head * 32 + qt) * NCH;

    float mi[NCH], li[NCH];
    float m = -3e38f;
    #pragma unroll
    for (int i = 0; i < NCH; ++i) {
        mi[i] = -3e38f; li[i] = 0.f;
        if (i < nch) {
            float2 v = Ml[(size_t)(base + i) * 64 + r];
            mi[i] = v.x; li[i] = v.y;
            m = fmaxf(m, v.x);
        }
    }
    float acc[32];
    #pragma unroll
    for (int u = 0; u < 32; ++u) acc[u] = 0.f;
    float l = 0.f;
    #pragma unroll
    for (int i = 0; i < NCH; ++i) {
        if (i < nch) {
            float w = __expf(mi[i] - m);
            l += w * li[i];
            const unsigned short* op = Opart + (size_t)(base + i) * 8192 + r * 128 + qc * 32;
            #pragma unroll
            for (int u = 0; u < 4; ++u) {
                short8v v8 = *(const short8v*)(op + u * 8);
                #pragma unroll
                for (int e = 0; e < 8; ++e)
                    acc[u * 8 + e] += w * __uint_as_float(((unsigned)(unsigned short)v8[e]) << 16);
            }
        }
    }
    float invl = 1.0f / l;
    unsigned short* dst = aob + (size_t)(qt * 64 + r) * 2048 + head * 128 + qc * 32;
    #pragma unroll
    for (int u = 0; u < 4; ++u) {
        short8v o8;
        #pragma unroll
        for (int e = 0; e < 8; ++e) o8[e] = (short)f2bf(acc[u * 8 + e] * invl);
        *(short8v*)(dst + u * 8) = o8;
    }
}

extern "C" void kernel_launch(void* const* d_in, const int* in_sizes, int n_in,
                              void* d_out, int out_size, void* d_ws, size_t ws_size,
                              hipStream_t stream)
{
    const float* x         = (const float*)d_in[0];
    const int*   positions = (const int*)  d_in[1];
    const float* w_q_a     = (const float*)d_in[2];
    const float* q_a_norm  = (const float*)d_in[3];
    const float* w_q_b     = (const float*)d_in[4];
    const float* w_kv_a    = (const float*)d_in[5];
    const float* kv_a_norm = (const float*)d_in[6];
    const float* w_kv_b    = (const float*)d_in[7];
    const float* w_o       = (const float*)d_in[8];
    float* out = (float*)d_out;

    // ---- workspace layout (~85.4 MB) ----
    float* q   = (float*)d_ws;                          // 2048*3072 f32 (later Kc/Vtc)
    float* kv  = q + (size_t)2048 * 3072;               // 2048*576 f32
    unsigned short* kvbb = (unsigned short*)(kv + (size_t)2048 * 576); // 2048*4096 bf16
    float* q_c = (float*)kvbb;                          // alias (dead before kvbb use)
    unsigned short* q_cb  = kvbb + (size_t)2048 * 4096; // 2048*1536
    unsigned short* kv_cb = q_cb + (size_t)2048 * 1536; // 2048*512
    unsigned short* xb    = kv_cb + (size_t)2048 * 512; // 2048*2048
    unsigned short* aob   = xb;                         // alias (xb dead before attn)
    unsigned short* qb    = xb + (size_t)2048 * 2048;   // 2048*16*192
    unsigned short* wbuf  = qb + (size_t)2048 * 3072;   // 3072*1536 max
    unsigned short* Kc    = (unsigned short*)q;         // 16*2048*192 (q dead after rope_qb)
    unsigned short* Vtc   = Kc + (size_t)16 * 2048 * 192; // 16*128*2048
    // partial scratch overlays kv+kvbb+q_cb+kv_cb (all dead by attn time): 29.9 MB
    unsigned short* Opart = (unsigned short*)kv;        // 1536*8192 bf16 = 25.2 MB
    float2* Ml = (float2*)(Opart + (size_t)1536 * 8192);// 1536*64*8B = 0.8 MB

    dim3 blk(256);

    // x -> bf16
    conv_bf16<<<(2048 * 2048 / 4 + 255) / 256, blk, 0, stream>>>(x, xb, 2048 * 2048 / 4);

    // G1: q_c = x @ w_q_a   (N=1536, K=2048) fp32 out
    wt_bf16<<<dim3(1536 / 32, 2048 / 32), blk, 0, stream>>>(w_q_a, wbuf, 2048, 1536);
    gemm_bf16<false><<<dim3(1536 / 128, 16), blk, 0, stream>>>(xb, wbuf, q_c, 1536, 2048, 1536);
    rmsnorm_bf16<<<2048, blk, 0, stream>>>(q_c, q_a_norm, q_cb, 1536);

    // G2: q = q_cb @ w_q_b  (N=3072, K=1536) fp32 out; then rope+pack -> qb
    wt_bf16<<<dim3(3072 / 32, 1536 / 32), blk, 0, stream>>>(w_q_b, wbuf, 1536, 3072);
    gemm_bf16<false><<<dim3(3072 / 128, 16), blk, 0, stream>>>(q_cb, wbuf, q, 3072, 1536, 3072);
    rope_qb<<<2048, dim3(192), 0, stream>>>(q, positions, qb);   // q dead after

    // G3: kv = x @ w_kv_a   (N=576, K=2048) fp32 out
    wt_bf16<<<dim3(576 / 32, 2048 / 32), blk, 0, stream>>>(w_kv_a, wbuf, 2048, 576);
    gemm_bf16<false><<<dim3(5, 16), blk, 0, stream>>>(xb, wbuf, kv, 576, 2048, 576);
    kv_fuse<<<2048, blk, 0, stream>>>(kv, kv_a_norm, positions, kv_cb);

    // G4: kvbb = kv_cb @ w_kv_b  (N=4096, K=512) bf16 out
    wt_bf16<<<dim3(4096 / 32, 512 / 32), blk, 0, stream>>>(w_kv_b, wbuf, 512, 4096);
    gemm_bf16<true><<<dim3(4096 / 128, 16), blk, 0, stream>>>(kv_cb, wbuf, kvbb, 4096, 512, 4096);

    // repack K and V^T caches (overwrites q's space)
    repack_k<<<2048, blk, 0, stream>>>(kvbb, kv, Kc);
    repack_vt<<<dim3(32, 32), blk, 0, stream>>>(kvbb, Vtc);

    // attention: 1536 KV-split jobs (chain <= 11 tiles) + combine
    attn_part<<<1536, blk, 0, stream>>>(qb, Kc, Vtc, Opart, Ml);
    attn_combine<<<512, blk, 0, stream>>>(Opart, Ml, aob);

    // G5: out = aob @ w_o   (N=2048, K=2048) fp32 out
    wt_bf16<<<dim3(2048 / 32, 2048 / 32), blk, 0, stream>>>(w_o, wbuf, 2048, 2048);
    gemm_bf16<false><<<dim3(2048 / 128, 16), blk, 0, stream>>>(aob, wbuf, out, 2048, 2048, 2048);
}

// Round 12
// 282.066 us; speedup vs baseline: 1.0545x; 1.0060x over previous
//
#include <hip/hip_runtime.h>
#include <hip/hip_bf16.h>
#include <math.h>

#define T_TOK   2048
#define NHEADS  16
#define EPS_    1e-6f
#define THETA_  10000.0f

typedef __attribute__((ext_vector_type(8))) short short8v;
typedef __attribute__((ext_vector_type(4))) float f32x4;

__device__ inline unsigned short f2bf(float f) {
    union { float f; unsigned u; } v; v.f = f;
    unsigned r = v.u + 0x7fffu + ((v.u >> 16) & 1u);
    return (unsigned short)(r >> 16);
}

// async global->LDS, 16B per lane; LDS dest is wave-uniform base + lane*16
__device__ __forceinline__ void gload16(const unsigned short* src, unsigned short* lds) {
    __builtin_amdgcn_global_load_lds(
        (const __attribute__((address_space(1))) unsigned int*)src,
        (__attribute__((address_space(3))) unsigned int*)lds, 16, 0, 0);
}

// ---------------- block-wide reduce (256 threads = 4 waves) ----------------
__device__ inline float block_reduce(float v, bool is_max, float* sred) {
    #pragma unroll
    for (int off = 32; off > 0; off >>= 1) {
        float o = __shfl_down(v, off, 64);
        v = is_max ? fmaxf(v, o) : (v + o);
    }
    int tid = threadIdx.x;
    __syncthreads();
    if ((tid & 63) == 0) sred[tid >> 6] = v;
    __syncthreads();
    float r = sred[0];
    #pragma unroll
    for (int w = 1; w < 4; ++w) r = is_max ? fmaxf(r, sred[w]) : (r + sred[w]);
    return r;
}

// ---------------- fp32 -> bf16 elementwise (n4 = n/4) ----------------
__global__ __launch_bounds__(256) void conv_bf16(const float* __restrict__ in,
    unsigned short* __restrict__ out, int n4)
{
    int i = blockIdx.x * 256 + threadIdx.x;
    if (i >= n4) return;
    float4 v = ((const float4*)in)[i];
    ushort4 o;
    o.x = f2bf(v.x); o.y = f2bf(v.y); o.z = f2bf(v.z); o.w = f2bf(v.w);
    ((ushort4*)out)[i] = o;
}

// ------------- fp32 [R][C] -> bf16 transposed [C][R] -------------
__global__ __launch_bounds__(256) void wt_bf16(const float* __restrict__ W,
    unsigned short* __restrict__ Wt, int R, int C)
{
    __shared__ float tile[32][33];
    int c0 = blockIdx.x * 32, r0 = blockIdx.y * 32;
    int tx = threadIdx.x & 31, ty = threadIdx.x >> 5;  // ty 0..7
    #pragma unroll
    for (int i = 0; i < 4; ++i)
        tile[ty + i * 8][tx] = W[(size_t)(r0 + ty + i * 8) * C + c0 + tx];
    __syncthreads();
    #pragma unroll
    for (int i = 0; i < 4; ++i)
        Wt[(size_t)(c0 + ty + i * 8) * R + r0 + tx] = f2bf(tile[tx][ty + i * 8]);
}

// =============== bf16 MFMA GEMM: C[M,N] = A[M,K] * Bt[N,K]^T ===============
// 128x128 tile, BK=64, 4 waves; dbuf + counted vmcnt (full K-step prefetch depth).
template<bool BF16OUT>
__global__ __launch_bounds__(256) void gemm_bf16(
    const unsigned short* __restrict__ A,   // [M][K] bf16
    const unsigned short* __restrict__ Bt,  // [>=gridX*128][K] bf16
    void* __restrict__ Cv, int N, int K, int ldc)
{
    __shared__ __align__(16) unsigned short As[2][128 * 64];
    __shared__ __align__(16) unsigned short Bs[2][128 * 64];
    const int tid = threadIdx.x;
    const int lane = tid & 63, wid = tid >> 6;
    const int wr = wid >> 1, wc = wid & 1;
    const int lrow = lane & 15, lkg = lane >> 4;
    const int r0 = blockIdx.y * 128, c0 = blockIdx.x * 128;

    f32x4 acc[4][4];
    #pragma unroll
    for (int m = 0; m < 4; ++m)
        #pragma unroll
        for (int n = 0; n < 4; ++n) acc[m][n] = (f32x4)0.f;

    // unit u = p*256+tid -> row r=u>>3, chunk cu=u&7; inverse-swizzled global src.
    #define STAGE_GEMM(buf, k0)                                                   \
        {   _Pragma("unroll")                                                     \
            for (int p = 0; p < 4; ++p) {                                         \
                int u = p * 256 + tid;                                            \
                int r = u >> 3, cu = u & 7;                                       \
                int dst = (p * 256 + wid * 64) * 8;                               \
                gload16(A  + (size_t)(r0 + r) * K + (k0) + ((cu ^ (r & 7)) << 3), \
                        As[buf] + dst);                                           \
                gload16(Bt + (size_t)(c0 + r) * K + (k0) + ((cu ^ (r & 7)) << 3), \
                        Bs[buf] + dst);                                           \
            }                                                                     \
        }

    STAGE_GEMM(0, 0)

    const int nkt = K >> 6;
    int buf = 0;
    for (int kt = 0; kt < nkt; ++kt) {
        if (kt + 1 < nkt) {
            STAGE_GEMM(buf ^ 1, (kt + 1) << 6)
            asm volatile("s_waitcnt vmcnt(8)" ::: "memory");   // tile kt landed
        } else {
            asm volatile("s_waitcnt vmcnt(0)" ::: "memory");
        }
        __builtin_amdgcn_s_barrier();
        #pragma unroll
        for (int ks = 0; ks < 2; ++ks) {
            short8v af[4], bf[4];
            #pragma unroll
            for (int m = 0; m < 4; ++m) {
                int row = wr * 64 + m * 16 + lrow;
                af[m] = *(const short8v*)((char*)As[buf] + row * 128 + (((ks * 4 + lkg) ^ (row & 7)) << 4));
            }
            #pragma unroll
            for (int n = 0; n < 4; ++n) {
                int row = wc * 64 + n * 16 + lrow;
                bf[n] = *(const short8v*)((char*)Bs[buf] + row * 128 + (((ks * 4 + lkg) ^ (row & 7)) << 4));
            }
            #pragma unroll
            for (int m = 0; m < 4; ++m)
                #pragma unroll
                for (int n = 0; n < 4; ++n)
                    acc[m][n] = __builtin_amdgcn_mfma_f32_16x16x32_bf16(af[m], bf[n], acc[m][n], 0, 0, 0);
        }
        __builtin_amdgcn_s_barrier();   // buf consumed before next STAGE overwrites
        buf ^= 1;
    }
    #undef STAGE_GEMM

    // D layout: col = lane&15, row = (lane>>4)*4 + j
    #pragma unroll
    for (int m = 0; m < 4; ++m) {
        int grow = r0 + wr * 64 + m * 16 + lkg * 4;
        #pragma unroll
        for (int n = 0; n < 4; ++n) {
            int gcol = c0 + wc * 64 + n * 16 + lrow;
            if (gcol < N) {
                #pragma unroll
                for (int j = 0; j < 4; ++j) {
                    if (BF16OUT)
                        ((unsigned short*)Cv)[(size_t)(grow + j) * ldc + gcol] = f2bf(acc[m][n][j]);
                    else
                        ((float*)Cv)[(size_t)(grow + j) * ldc + gcol] = acc[m][n][j];
                }
            }
        }
    }
}

// ---------------- RMSNorm rows -> bf16 ----------------
__global__ __launch_bounds__(256) void rmsnorm_bf16(const float* __restrict__ y,
    const float* __restrict__ g, unsigned short* __restrict__ o, int width)
{
    __shared__ float sred[4];
    int row = blockIdx.x;
    const float* p = y + (size_t)row * width;
    float ss = 0.f;
    for (int i = threadIdx.x; i < width; i += 256) { float v = p[i]; ss += v * v; }
    ss = block_reduce(ss, false, sred);
    float sc = rsqrtf(ss / (float)width + EPS_);
    for (int i = threadIdx.x; i < width; i += 256)
        o[(size_t)row * width + i] = f2bf(p[i] * sc * g[i]);
}

// -- kv row: rmsnorm first 512 -> bf16 out ; RoPE cols 512..575 fp32 inplace --
__global__ __launch_bounds__(256) void kv_fuse(float* __restrict__ kv,
    const float* __restrict__ g, const int* __restrict__ positions,
    unsigned short* __restrict__ kvcb)
{
    __shared__ float sred[4];
    int row = blockIdx.x;
    float* p = kv + (size_t)row * 576;
    float ss = 0.f;
    for (int i = threadIdx.x; i < 512; i += 256) { float v = p[i]; ss += v * v; }
    ss = block_reduce(ss, false, sred);
    float sc = rsqrtf(ss / 512.0f + EPS_);
    for (int i = threadIdx.x; i < 512; i += 256)
        kvcb[(size_t)row * 512 + i] = f2bf(p[i] * sc * g[i]);
    if (threadIdx.x < 32) {
        int i = threadIdx.x;
        float pos = (float)positions[row];
        float inv = powf(THETA_, -(float)i / 32.0f);
        float ang = pos * inv;
        float c = cosf(ang), s = sinf(ang);
        float x1 = p[512 + i], x2 = p[544 + i];
        p[512 + i] = x1 * c - x2 * s;
        p[544 + i] = x2 * c + x1 * s;
    }
}

// -------- RoPE + scale + bf16 pack of q: [T][3072] f32 -> [T][16][192] bf16 --------
__global__ __launch_bounds__(192) void rope_qb(const float* __restrict__ q,
    const int* __restrict__ positions, unsigned short* __restrict__ qb)
{
    int t = blockIdx.x, d = threadIdx.x;
    const float scale = 0.07216878364870323f;  // (128+64)^-0.5
    float c = 1.f, s = 0.f;
    if (d >= 128) {
        int i = (d - 128) & 31;
        float pos = (float)positions[t];
        float inv = powf(THETA_, -(float)i / 32.0f);
        float ang = pos * inv;
        c = cosf(ang); s = sinf(ang);
    }
    #pragma unroll 4
    for (int n = 0; n < 16; ++n) {
        const float* p = q + (size_t)t * 3072 + n * 192;
        float v;
        if (d < 128)      v = p[d];
        else if (d < 160) v = p[d] * c - p[d + 32] * s;
        else              v = p[d] * c + p[d - 32] * s;
        qb[((size_t)t * 16 + n) * 192 + d] = f2bf(v * scale);
    }
}

// -------- K cache: [16][T][192] bf16 = k_nope (from kvb bf16) + roped k_pe --------
__global__ __launch_bounds__(256) void repack_k(const unsigned short* __restrict__ kvbb,
    const float* __restrict__ kv, unsigned short* __restrict__ Kc)
{
    int t = blockIdx.x, tid = threadIdx.x;
    int n = tid >> 4;
    int c8 = tid & 15;
    short8v v = *(const short8v*)(kvbb + ((size_t)t * 16 + n) * 256 + c8 * 8);
    *(short8v*)(Kc + ((size_t)n * 2048 + t) * 192 + c8 * 8) = v;
    int i4 = (tid & 15) * 4;
    float4 p = *(const float4*)(kv + (size_t)t * 576 + 512 + i4);
    ushort4 o; o.x = f2bf(p.x); o.y = f2bf(p.y); o.z = f2bf(p.z); o.w = f2bf(p.w);
    *(ushort4*)(Kc + ((size_t)n * 2048 + t) * 192 + 128 + i4) = o;
}

// -------- V^T cache: [16][128][T] bf16, LDS-tiled 64x64 transpose --------
__global__ __launch_bounds__(256) void repack_vt(const unsigned short* __restrict__ kvbb,
    unsigned short* __restrict__ Vtc)
{
    __shared__ unsigned short tile[64][72];
    int t0 = blockIdx.x * 64;
    int n = blockIdx.y >> 1, dv0 = (blockIdx.y & 1) * 64;
    int tid = threadIdx.x;
    for (int u = tid; u < 512; u += 256) {
        int t = u >> 3, c8 = u & 7;
        short8v v = *(const short8v*)(kvbb + ((size_t)(t0 + t) * 16 + n) * 256 + 128 + dv0 + c8 * 8);
        *(short8v*)(&tile[t][c8 * 8]) = v;
    }
    __syncthreads();
    for (int u = tid; u < 512; u += 256) {
        int dv = u & 63, t8 = u >> 6;
        short8v v;
        #pragma unroll
        for (int e = 0; e < 8; ++e) v[e] = (short)tile[t8 * 8 + e][dv];
        *(short8v*)(Vtc + ((size_t)n * 128 + dv0 + dv) * 2048 + t0 + t8 * 8) = v;
    }
}

// ======== MFMA flash attention, KV-split jobs, K-dbuf counted-vmcnt pipeline ========
#define QBLK  64
#define KVBLK 64
#define NCH   3

__global__ __launch_bounds__(256) void attn_part(
    const unsigned short* __restrict__ qb,    // [T][16][192] bf16 (scale folded)
    const unsigned short* __restrict__ Kc,    // [16][T][192] bf16
    const unsigned short* __restrict__ Vtc,   // [16][128][T] bf16
    unsigned short* __restrict__ Opart,       // [1536][64][128] bf16 unnormalized
    float2* __restrict__ Ml)                  // [1536][64] (m, l)
{
    __shared__ __align__(16) unsigned short Ks[2][KVBLK * 192]; // 2x24 KB
    __shared__ __align__(16) unsigned short Vt[128 * KVBLK];    // 16 KB
    __shared__ __align__(16) unsigned short Ps[4][16 * KVBLK];  //  8 KB (72 total)

    // job map: xcd = bid&7 (2 heads/XCD), heavy qt first within head
    const int bid = blockIdx.x;               // 0..1535
    const int xcd = bid & 7;
    const int j   = bid >> 3;                 // 0..191
    const int n   = xcd * 2 + (j >= 96);
    const int jj  = (j >= 96) ? j - 96 : j;   // 0..95
    const int qt  = 31 - (jj / NCH);
    const int ch  = jj % NCH;

    const int nt  = qt + 1;
    const int csz = (nt + NCH - 1) / NCH;
    const int tstart = ch * csz;
    if (tstart >= nt) return;                 // empty chunk
    const int tend = min(tstart + csz, nt);

    const int tid = threadIdx.x;
    const int lane = tid & 63, wid = tid >> 6;
    const int lrow = lane & 15;
    const int lkg  = lane >> 4;
    const int q0 = qt * QBLK;
    const int pidx = ((n * 32 + qt) * NCH + ch);

    const unsigned short* Kh = Kc  + (size_t)n * 2048 * 192;
    const unsigned short* Vh = Vtc + (size_t)n * 128 * 2048;

    // ---- hoisted staging offsets ----
    int koff[6], voff[4];
    #pragma unroll
    for (int p = 0; p < 6; ++p) {
        int u = p * 256 + tid;
        int row = u / 24, c8 = u % 24;
        koff[p] = row * 192 + ((c8 ^ (row & 7)) << 3);
    }
    #pragma unroll
    for (int p = 0; p < 4; ++p) {
        int u = p * 256 + tid;
        int dv = u >> 3, c8 = u & 7;
        voff[p] = dv * 2048 + ((c8 ^ (dv & 7)) << 3);
    }

    // ---- Q fragments ----
    short8v qf[6];
    {
        const unsigned short* qrow = qb + ((size_t)(q0 + wid * 16 + lrow) * 16 + n) * 192;
        #pragma unroll
        for (int ds = 0; ds < 6; ++ds)
            qf[ds] = *(const short8v*)(qrow + ds * 32 + lkg * 8);
    }

    f32x4 oacc[8];
    #pragma unroll
    for (int i = 0; i < 8; ++i) oacc[i] = (f32x4)0.f;
    float mrow[4] = {-3e38f, -3e38f, -3e38f, -3e38f};
    float lsum[4] = {0.f, 0.f, 0.f, 0.f};

    // ---- prologue: issue K[tstart] (6) then V[tstart] (4) ----
    #pragma unroll
    for (int p = 0; p < 6; ++p)
        gload16(Kh + (size_t)tstart * KVBLK * 192 + koff[p], Ks[0] + (p * 256 + wid * 64) * 8);
    #pragma unroll
    for (int p = 0; p < 4; ++p)
        gload16(Vh + tstart * KVBLK + voff[p], Vt + (p * 256 + wid * 64) * 8);

    int buf = 0;
    for (int tile = tstart; tile < tend; ++tile) {
        const int s0 = tile * KVBLK;
        const bool more = (tile + 1 < tend);

        // ---- issue K[t+1] at tile TOP (full-tile latency depth) ----
        if (more) {
            #pragma unroll
            for (int p = 0; p < 6; ++p)
                gload16(Kh + (size_t)(s0 + KVBLK) * 192 + koff[p],
                        Ks[buf ^ 1] + (p * 256 + wid * 64) * 8);
            asm volatile("s_waitcnt vmcnt(10)" ::: "memory");  // K[t] landed; V[t]+K[t+1] fly
        } else {
            asm volatile("s_waitcnt vmcnt(4)" ::: "memory");   // K[t] landed; V[t] flies
        }
        __builtin_amdgcn_s_barrier();

        // ---- S = Q K^T from Ks[buf] ----
        f32x4 sacc[4];
        #pragma unroll
        for (int ct = 0; ct < 4; ++ct) sacc[ct] = (f32x4)0.f;
        __builtin_amdgcn_s_setprio(1);
        #pragma unroll
        for (int ds = 0; ds < 6; ++ds) {
            #pragma unroll
            for (int ct = 0; ct < 4; ++ct) {
                int krow = ct * 16 + lrow;
                int byte = (krow * 384 + ds * 64 + lkg * 16) ^ ((krow & 7) << 4);
                short8v bf = *(const short8v*)((char*)Ks[buf] + byte);
                sacc[ct] = __builtin_amdgcn_mfma_f32_16x16x32_bf16(qf[ds], bf, sacc[ct], 0, 0, 0);
            }
        }
        __builtin_amdgcn_s_setprio(0);

        // ---- causal mask ----
        #pragma unroll
        for (int ct = 0; ct < 4; ++ct) {
            int key = s0 + ct * 16 + lrow;
            #pragma unroll
            for (int jq = 0; jq < 4; ++jq) {
                int gqr = q0 + wid * 16 + lkg * 4 + jq;
                if (key > gqr) sacc[ct][jq] = -3e38f;
            }
        }

        // ---- online softmax (all-masked rows -> p = 0) ----
        float corr[4];
        #pragma unroll
        for (int jq = 0; jq < 4; ++jq) {
            float tm = fmaxf(fmaxf(sacc[0][jq], sacc[1][jq]), fmaxf(sacc[2][jq], sacc[3][jq]));
            #pragma unroll
            for (int w2 = 1; w2 < 16; w2 <<= 1) tm = fmaxf(tm, __shfl_xor(tm, w2, 16));
            float mn = fmaxf(mrow[jq], tm);
            corr[jq] = __expf(mrow[jq] - mn);
            mrow[jq] = mn;
        }
        float psum[4] = {0.f, 0.f, 0.f, 0.f};
        unsigned short pb[4][4];
        #pragma unroll
        for (int ct = 0; ct < 4; ++ct)
            #pragma unroll
            for (int jq = 0; jq < 4; ++jq) {
                float sv = sacc[ct][jq];
                float p = (sv > -1e37f) ? __expf(sv - mrow[jq]) : 0.f;
                psum[jq] += p;
                pb[ct][jq] = f2bf(p);
            }
        #pragma unroll
        for (int jq = 0; jq < 4; ++jq) {
            float ps = psum[jq];
            #pragma unroll
            for (int w2 = 1; w2 < 16; w2 <<= 1) ps += __shfl_xor(ps, w2, 16);
            lsum[jq] = lsum[jq] * corr[jq] + ps;
        }
        #pragma unroll
        for (int dt = 0; dt < 8; ++dt)
            #pragma unroll
            for (int jq = 0; jq < 4; ++jq) oacc[dt][jq] *= corr[jq];

        // ---- P -> per-wave LDS ----
        #pragma unroll
        for (int ct = 0; ct < 4; ++ct)
            #pragma unroll
            for (int jq = 0; jq < 4; ++jq) {
                int r = lkg * 4 + jq, c = ct * 16 + lrow;
                int byte = ((r * 64 + c) * 2) ^ ((r & 7) << 4);
                *(unsigned short*)((char*)Ps[wid] + byte) = pb[ct][jq];
            }

        // ---- V[t] landed (K[t+1] stays in flight) ----
        if (more) asm volatile("s_waitcnt vmcnt(6)" ::: "memory");
        else      asm volatile("s_waitcnt vmcnt(0)" ::: "memory");
        __builtin_amdgcn_s_barrier();

        // ---- O += P V ----
        __builtin_amdgcn_s_setprio(1);
        #pragma unroll
        for (int ks = 0; ks < 2; ++ks) {
            int abyte = ((lrow * 64 + ks * 32 + lkg * 8) * 2) ^ ((lrow & 7) << 4);
            short8v af = *(const short8v*)((char*)Ps[wid] + abyte);
            #pragma unroll
            for (int dt = 0; dt < 8; ++dt) {
                int vrow = dt * 16 + lrow;
                int byte = ((vrow * 128 + ks * 64 + lkg * 16)) ^ ((vrow & 7) << 4);
                short8v bf = *(const short8v*)((char*)Vt + byte);
                oacc[dt] = __builtin_amdgcn_mfma_f32_16x16x32_bf16(af, bf, oacc[dt], 0, 0, 0);
            }
        }
        __builtin_amdgcn_s_setprio(0);

        __builtin_amdgcn_s_barrier();      // Vt consumed by all waves
        // ---- issue V[t+1] (lands under next tile's QK^T+softmax) ----
        if (more) {
            #pragma unroll
            for (int p = 0; p < 4; ++p)
                gload16(Vh + (s0 + KVBLK) + voff[p], Vt + (p * 256 + wid * 64) * 8);
        }
        buf ^= 1;
    }

    // ---- write partials (unnormalized O bf16, m/l fp32) ----
    #pragma unroll
    for (int dt = 0; dt < 8; ++dt)
        #pragma unroll
        for (int jq = 0; jq < 4; ++jq) {
            int row = wid * 16 + lkg * 4 + jq;
            Opart[(size_t)pidx * 8192 + row * 128 + dt * 16 + lrow] = f2bf(oacc[dt][jq]);
        }
    if (lrow == 0) {
        #pragma unroll
        for (int jq = 0; jq < 4; ++jq) {
            int row = wid * 16 + lkg * 4 + jq;
            Ml[(size_t)pidx * 64 + row] = make_float2(mrow[jq], lsum[jq]);
        }
    }
}

// -------- combine <=3 partials per (head, qtile) -> bf16 attention out --------
__global__ __launch_bounds__(256) void attn_combine(
    const unsigned short* __restrict__ Opart, const float2* __restrict__ Ml,
    unsigned short* __restrict__ aob)
{
    const int bid = blockIdx.x;               // 512 = head*32 + qt
    const int head = bid >> 5, qt = bid & 31;
    const int nt = qt + 1, csz = (nt + NCH - 1) / NCH;
    const int nch = (nt + csz - 1) / csz;
    const int tid = threadIdx.x;
    const int r = tid >> 2, qc = tid & 3;     // row 0..63, col-quarter
    const int base = (head * 32 + qt) * NCH;

    float mi[NCH], li[NCH];
    float m = -3e38f;
    #pragma unroll
    for (int i = 0; i < NCH; ++i) {
        mi[i] = -3e38f; li[i] = 0.f;
        if (i < nch) {
            float2 v = Ml[(size_t)(base + i) * 64 + r];
            mi[i] = v.x; li[i] = v.y;
            m = fmaxf(m, v.x);
        }
    }
    float acc[32];
    #pragma unroll
    for (int u = 0; u < 32; ++u) acc[u] = 0.f;
    float l = 0.f;
    #pragma unroll
    for (int i = 0; i < NCH; ++i) {
        if (i < nch) {
            float w = __expf(mi[i] - m);
            l += w * li[i];
            const unsigned short* op = Opart + (size_t)(base + i) * 8192 + r * 128 + qc * 32;
            #pragma unroll
            for (int u = 0; u < 4; ++u) {
                short8v v8 = *(const short8v*)(op + u * 8);
                #pragma unroll
                for (int e = 0; e < 8; ++e)
                    acc[u * 8 + e] += w * __uint_as_float(((unsigned)(unsigned short)v8[e]) << 16);
            }
        }
    }
    float invl = 1.0f / l;
    unsigned short* dst = aob + (size_t)(qt * 64 + r) * 2048 + head * 128 + qc * 32;
    #pragma unroll
    for (int u = 0; u < 4; ++u) {
        short8v o8;
        #pragma unroll
        for (int e = 0; e < 8; ++e) o8[e] = (short)f2bf(acc[u * 8 + e] * invl);
        *(short8v*)(dst + u * 8) = o8;
    }
}

extern "C" void kernel_launch(void* const* d_in, const int* in_sizes, int n_in,
                              void* d_out, int out_size, void* d_ws, size_t ws_size,
                              hipStream_t stream)
{
    const float* x         = (const float*)d_in[0];
    const int*   positions = (const int*)  d_in[1];
    const float* w_q_a     = (const float*)d_in[2];
    const float* q_a_norm  = (const float*)d_in[3];
    const float* w_q_b     = (const float*)d_in[4];
    const float* w_kv_a    = (const float*)d_in[5];
    const float* kv_a_norm = (const float*)d_in[6];
    const float* w_kv_b    = (const float*)d_in[7];
    const float* w_o       = (const float*)d_in[8];
    float* out = (float*)d_out;

    // ---- workspace layout (~85.4 MB) ----
    float* q   = (float*)d_ws;                          // 2048*3072 f32 (later Kc/Vtc)
    float* kv  = q + (size_t)2048 * 3072;               // 2048*576 f32
    unsigned short* kvbb = (unsigned short*)(kv + (size_t)2048 * 576); // 2048*4096 bf16
    float* q_c = (float*)kvbb;                          // alias (dead before kvbb use)
    unsigned short* q_cb  = kvbb + (size_t)2048 * 4096; // 2048*1536
    unsigned short* kv_cb = q_cb + (size_t)2048 * 1536; // 2048*512
    unsigned short* xb    = kv_cb + (size_t)2048 * 512; // 2048*2048
    unsigned short* aob   = xb;                         // alias (xb dead before attn)
    unsigned short* qb    = xb + (size_t)2048 * 2048;   // 2048*16*192
    unsigned short* wbuf  = qb + (size_t)2048 * 3072;   // 3072*1536 max
    unsigned short* Kc    = (unsigned short*)q;         // 16*2048*192 (q dead after rope_qb)
    unsigned short* Vtc   = Kc + (size_t)16 * 2048 * 192; // 16*128*2048
    // partial scratch overlays kv+kvbb+q_cb+kv_cb (all dead by attn time): 29.9 MB
    unsigned short* Opart = (unsigned short*)kv;        // 1536*8192 bf16 = 25.2 MB
    float2* Ml = (float2*)(Opart + (size_t)1536 * 8192);// 1536*64*8B = 0.8 MB

    dim3 blk(256);

    // x -> bf16
    conv_bf16<<<(2048 * 2048 / 4 + 255) / 256, blk, 0, stream>>>(x, xb, 2048 * 2048 / 4);

    // G1: q_c = x @ w_q_a   (N=1536, K=2048) fp32 out
    wt_bf16<<<dim3(1536 / 32, 2048 / 32), blk, 0, stream>>>(w_q_a, wbuf, 2048, 1536);
    gemm_bf16<false><<<dim3(1536 / 128, 16), blk, 0, stream>>>(xb, wbuf, q_c, 1536, 2048, 1536);
    rmsnorm_bf16<<<2048, blk, 0, stream>>>(q_c, q_a_norm, q_cb, 1536);

    // G2: q = q_cb @ w_q_b  (N=3072, K=1536) fp32 out; then rope+pack -> qb
    wt_bf16<<<dim3(3072 / 32, 1536 / 32), blk, 0, stream>>>(w_q_b, wbuf, 1536, 3072);
    gemm_bf16<false><<<dim3(3072 / 128, 16), blk, 0, stream>>>(q_cb, wbuf, q, 3072, 1536, 3072);
    rope_qb<<<2048, dim3(192), 0, stream>>>(q, positions, qb);   // q dead after

    // G3: kv = x @ w_kv_a   (N=576, K=2048) fp32 out
    wt_bf16<<<dim3(576 / 32, 2048 / 32), blk, 0, stream>>>(w_kv_a, wbuf, 2048, 576);
    gemm_bf16<false><<<dim3(5, 16), blk, 0, stream>>>(xb, wbuf, kv, 576, 2048, 576);
    kv_fuse<<<2048, blk, 0, stream>>>(kv, kv_a_norm, positions, kv_cb);

    // G4: kvbb = kv_cb @ w_kv_b  (N=4096, K=512) bf16 out
    wt_bf16<<<dim3(4096 / 32, 512 / 32), blk, 0, stream>>>(w_kv_b, wbuf, 512, 4096);
    gemm_bf16<true><<<dim3(4096 / 128, 16), blk, 0, stream>>>(kv_cb, wbuf, kvbb, 4096, 512, 4096);

    // repack K and V^T caches (overwrites q's space)
    repack_k<<<2048, blk, 0, stream>>>(kvbb, kv, Kc);
    repack_vt<<<dim3(32, 32), blk, 0, stream>>>(kvbb, Vtc);

    // attention: 1536 KV-split jobs (chain <= 11 tiles), K-dbuf pipeline + combine
    attn_part<<<1536, blk, 0, stream>>>(qb, Kc, Vtc, Opart, Ml);
    attn_combine<<<512, blk, 0, stream>>>(Opart, Ml, aob);

    // G5: out = aob @ w_o   (N=2048, K=2048) fp32 out
    wt_bf16<<<dim3(2048 / 32, 2048 / 32), blk, 0, stream>>>(w_o, wbuf, 2048, 2048);
    gemm_bf16<false><<<dim3(2048 / 128, 16), blk, 0, stream>>>(aob, wbuf, out, 2048, 2048, 2048);
}

// Round 13
// 273.320 us; speedup vs baseline: 1.0882x; 1.0320x over previous
//
#include <hip/hip_runtime.h>
#include <hip/hip_bf16.h>
#include <math.h>

#define T_TOK   2048
#define NHEADS  16
#define EPS_    1e-6f
#define THETA_  10000.0f

typedef __attribute__((ext_vector_type(8))) short short8v;
typedef __attribute__((ext_vector_type(4))) float f32x4;

__device__ inline unsigned short f2bf(float f) {
    union { float f; unsigned u; } v; v.f = f;
    unsigned r = v.u + 0x7fffu + ((v.u >> 16) & 1u);
    return (unsigned short)(r >> 16);
}

// async global->LDS, 16B per lane; LDS dest is wave-uniform base + lane*16
__device__ __forceinline__ void gload16(const unsigned short* src, unsigned short* lds) {
    __builtin_amdgcn_global_load_lds(
        (const __attribute__((address_space(1))) unsigned int*)src,
        (__attribute__((address_space(3))) unsigned int*)lds, 16, 0, 0);
}

// ---------------- block-wide reduce (256 threads = 4 waves) ----------------
__device__ inline float block_reduce(float v, bool is_max, float* sred) {
    #pragma unroll
    for (int off = 32; off > 0; off >>= 1) {
        float o = __shfl_down(v, off, 64);
        v = is_max ? fmaxf(v, o) : (v + o);
    }
    int tid = threadIdx.x;
    __syncthreads();
    if ((tid & 63) == 0) sred[tid >> 6] = v;
    __syncthreads();
    float r = sred[0];
    #pragma unroll
    for (int w = 1; w < 4; ++w) r = is_max ? fmaxf(r, sred[w]) : (r + sred[w]);
    return r;
}

// ---------------- fp32 -> bf16 elementwise (n4 = n/4) ----------------
__global__ __launch_bounds__(256) void conv_bf16(const float* __restrict__ in,
    unsigned short* __restrict__ out, int n4)
{
    int i = blockIdx.x * 256 + threadIdx.x;
    if (i >= n4) return;
    float4 v = ((const float4*)in)[i];
    ushort4 o;
    o.x = f2bf(v.x); o.y = f2bf(v.y); o.z = f2bf(v.z); o.w = f2bf(v.w);
    ((ushort4*)out)[i] = o;
}

// ------------- fp32 [R][C] -> bf16 transposed [C][R] -------------
__global__ __launch_bounds__(256) void wt_bf16(const float* __restrict__ W,
    unsigned short* __restrict__ Wt, int R, int C)
{
    __shared__ float tile[32][33];
    int c0 = blockIdx.x * 32, r0 = blockIdx.y * 32;
    int tx = threadIdx.x & 31, ty = threadIdx.x >> 5;  // ty 0..7
    #pragma unroll
    for (int i = 0; i < 4; ++i)
        tile[ty + i * 8][tx] = W[(size_t)(r0 + ty + i * 8) * C + c0 + tx];
    __syncthreads();
    #pragma unroll
    for (int i = 0; i < 4; ++i)
        Wt[(size_t)(c0 + ty + i * 8) * R + r0 + tx] = f2bf(tile[tx][ty + i * 8]);
}

// =============== bf16 MFMA GEMM: C[M,N] = A[M,K] * Bt[N,K]^T ===============
// 128x128 tile, BK=64, 4 waves; dbuf + counted vmcnt (full K-step prefetch depth).
template<bool BF16OUT>
__global__ __launch_bounds__(256) void gemm_bf16(
    const unsigned short* __restrict__ A,   // [M][K] bf16
    const unsigned short* __restrict__ Bt,  // [>=gridX*128][K] bf16
    void* __restrict__ Cv, int N, int K, int ldc)
{
    __shared__ __align__(16) unsigned short As[2][128 * 64];
    __shared__ __align__(16) unsigned short Bs[2][128 * 64];
    const int tid = threadIdx.x;
    const int lane = tid & 63, wid = tid >> 6;
    const int wr = wid >> 1, wc = wid & 1;
    const int lrow = lane & 15, lkg = lane >> 4;
    const int r0 = blockIdx.y * 128, c0 = blockIdx.x * 128;

    f32x4 acc[4][4];
    #pragma unroll
    for (int m = 0; m < 4; ++m)
        #pragma unroll
        for (int n = 0; n < 4; ++n) acc[m][n] = (f32x4)0.f;

    // unit u = p*256+tid -> row r=u>>3, chunk cu=u&7; inverse-swizzled global src.
    #define STAGE_GEMM(buf, k0)                                                   \
        {   _Pragma("unroll")                                                     \
            for (int p = 0; p < 4; ++p) {                                         \
                int u = p * 256 + tid;                                            \
                int r = u >> 3, cu = u & 7;                                       \
                int dst = (p * 256 + wid * 64) * 8;                               \
                gload16(A  + (size_t)(r0 + r) * K + (k0) + ((cu ^ (r & 7)) << 3), \
                        As[buf] + dst);                                           \
                gload16(Bt + (size_t)(c0 + r) * K + (k0) + ((cu ^ (r & 7)) << 3), \
                        Bs[buf] + dst);                                           \
            }                                                                     \
        }

    STAGE_GEMM(0, 0)

    const int nkt = K >> 6;
    int buf = 0;
    for (int kt = 0; kt < nkt; ++kt) {
        if (kt + 1 < nkt) {
            STAGE_GEMM(buf ^ 1, (kt + 1) << 6)
            asm volatile("s_waitcnt vmcnt(8)" ::: "memory");   // tile kt landed
        } else {
            asm volatile("s_waitcnt vmcnt(0)" ::: "memory");
        }
        __builtin_amdgcn_s_barrier();
        #pragma unroll
        for (int ks = 0; ks < 2; ++ks) {
            short8v af[4], bf[4];
            #pragma unroll
            for (int m = 0; m < 4; ++m) {
                int row = wr * 64 + m * 16 + lrow;
                af[m] = *(const short8v*)((char*)As[buf] + row * 128 + (((ks * 4 + lkg) ^ (row & 7)) << 4));
            }
            #pragma unroll
            for (int n = 0; n < 4; ++n) {
                int row = wc * 64 + n * 16 + lrow;
                bf[n] = *(const short8v*)((char*)Bs[buf] + row * 128 + (((ks * 4 + lkg) ^ (row & 7)) << 4));
            }
            #pragma unroll
            for (int m = 0; m < 4; ++m)
                #pragma unroll
                for (int n = 0; n < 4; ++n)
                    acc[m][n] = __builtin_amdgcn_mfma_f32_16x16x32_bf16(af[m], bf[n], acc[m][n], 0, 0, 0);
        }
        __builtin_amdgcn_s_barrier();   // buf consumed before next STAGE overwrites
        buf ^= 1;
    }
    #undef STAGE_GEMM

    // D layout: col = lane&15, row = (lane>>4)*4 + j
    #pragma unroll
    for (int m = 0; m < 4; ++m) {
        int grow = r0 + wr * 64 + m * 16 + lkg * 4;
        #pragma unroll
        for (int n = 0; n < 4; ++n) {
            int gcol = c0 + wc * 64 + n * 16 + lrow;
            if (gcol < N) {
                #pragma unroll
                for (int j = 0; j < 4; ++j) {
                    if (BF16OUT)
                        ((unsigned short*)Cv)[(size_t)(grow + j) * ldc + gcol] = f2bf(acc[m][n][j]);
                    else
                        ((float*)Cv)[(size_t)(grow + j) * ldc + gcol] = acc[m][n][j];
                }
            }
        }
    }
}

// ---------------- RMSNorm rows -> bf16 ----------------
__global__ __launch_bounds__(256) void rmsnorm_bf16(const float* __restrict__ y,
    const float* __restrict__ g, unsigned short* __restrict__ o, int width)
{
    __shared__ float sred[4];
    int row = blockIdx.x;
    const float* p = y + (size_t)row * width;
    float ss = 0.f;
    for (int i = threadIdx.x; i < width; i += 256) { float v = p[i]; ss += v * v; }
    ss = block_reduce(ss, false, sred);
    float sc = rsqrtf(ss / (float)width + EPS_);
    for (int i = threadIdx.x; i < width; i += 256)
        o[(size_t)row * width + i] = f2bf(p[i] * sc * g[i]);
}

// -- kv row: rmsnorm first 512 -> bf16 out ; RoPE cols 512..575 fp32 inplace --
__global__ __launch_bounds__(256) void kv_fuse(float* __restrict__ kv,
    const float* __restrict__ g, const int* __restrict__ positions,
    unsigned short* __restrict__ kvcb)
{
    __shared__ float sred[4];
    int row = blockIdx.x;
    float* p = kv + (size_t)row * 576;
    float ss = 0.f;
    for (int i = threadIdx.x; i < 512; i += 256) { float v = p[i]; ss += v * v; }
    ss = block_reduce(ss, false, sred);
    float sc = rsqrtf(ss / 512.0f + EPS_);
    for (int i = threadIdx.x; i < 512; i += 256)
        kvcb[(size_t)row * 512 + i] = f2bf(p[i] * sc * g[i]);
    if (threadIdx.x < 32) {
        int i = threadIdx.x;
        float pos = (float)positions[row];
        float inv = powf(THETA_, -(float)i / 32.0f);
        float ang = pos * inv;
        float c = cosf(ang), s = sinf(ang);
        float x1 = p[512 + i], x2 = p[544 + i];
        p[512 + i] = x1 * c - x2 * s;
        p[544 + i] = x2 * c + x1 * s;
    }
}

// -------- RoPE + scale + bf16 pack of q: [T][3072] f32 -> [T][16][192] bf16 --------
__global__ __launch_bounds__(192) void rope_qb(const float* __restrict__ q,
    const int* __restrict__ positions, unsigned short* __restrict__ qb)
{
    int t = blockIdx.x, d = threadIdx.x;
    const float scale = 0.07216878364870323f;  // (128+64)^-0.5
    float c = 1.f, s = 0.f;
    if (d >= 128) {
        int i = (d - 128) & 31;
        float pos = (float)positions[t];
        float inv = powf(THETA_, -(float)i / 32.0f);
        float ang = pos * inv;
        c = cosf(ang); s = sinf(ang);
    }
    #pragma unroll 4
    for (int n = 0; n < 16; ++n) {
        const float* p = q + (size_t)t * 3072 + n * 192;
        float v;
        if (d < 128)      v = p[d];
        else if (d < 160) v = p[d] * c - p[d + 32] * s;
        else              v = p[d] * c + p[d - 32] * s;
        qb[((size_t)t * 16 + n) * 192 + d] = f2bf(v * scale);
    }
}

// -------- K cache: [16][T][192] bf16 = k_nope (from kvb bf16) + roped k_pe --------
__global__ __launch_bounds__(256) void repack_k(const unsigned short* __restrict__ kvbb,
    const float* __restrict__ kv, unsigned short* __restrict__ Kc)
{
    int t = blockIdx.x, tid = threadIdx.x;
    int n = tid >> 4;
    int c8 = tid & 15;
    short8v v = *(const short8v*)(kvbb + ((size_t)t * 16 + n) * 256 + c8 * 8);
    *(short8v*)(Kc + ((size_t)n * 2048 + t) * 192 + c8 * 8) = v;
    int i4 = (tid & 15) * 4;
    float4 p = *(const float4*)(kv + (size_t)t * 576 + 512 + i4);
    ushort4 o; o.x = f2bf(p.x); o.y = f2bf(p.y); o.z = f2bf(p.z); o.w = f2bf(p.w);
    *(ushort4*)(Kc + ((size_t)n * 2048 + t) * 192 + 128 + i4) = o;
}

// -------- V^T cache: [16][128][T] bf16, LDS-tiled 64x64 transpose --------
__global__ __launch_bounds__(256) void repack_vt(const unsigned short* __restrict__ kvbb,
    unsigned short* __restrict__ Vtc)
{
    __shared__ unsigned short tile[64][72];
    int t0 = blockIdx.x * 64;
    int n = blockIdx.y >> 1, dv0 = (blockIdx.y & 1) * 64;
    int tid = threadIdx.x;
    for (int u = tid; u < 512; u += 256) {
        int t = u >> 3, c8 = u & 7;
        short8v v = *(const short8v*)(kvbb + ((size_t)(t0 + t) * 16 + n) * 256 + 128 + dv0 + c8 * 8);
        *(short8v*)(&tile[t][c8 * 8]) = v;
    }
    __syncthreads();
    for (int u = tid; u < 512; u += 256) {
        int dv = u & 63, t8 = u >> 6;
        short8v v;
        #pragma unroll
        for (int e = 0; e < 8; ++e) v[e] = (short)tile[t8 * 8 + e][dv];
        *(short8v*)(Vtc + ((size_t)n * 128 + dv0 + dv) * 2048 + t0 + t8 * 8) = v;
    }
}

// ==== MFMA flash attention, KV-split, swapped-QK^T in-lane softmax ====
#define QBLK  64
#define KVBLK 64
#define NCH   3

__global__ __launch_bounds__(256) void attn_part(
    const unsigned short* __restrict__ qb,    // [T][16][192] bf16 (scale folded)
    const unsigned short* __restrict__ Kc,    // [16][T][192] bf16
    const unsigned short* __restrict__ Vtc,   // [16][128][T] bf16
    unsigned short* __restrict__ Opart,       // [1536][64][128] bf16 unnormalized
    float2* __restrict__ Ml)                  // [1536][64] (m, l)
{
    __shared__ __align__(16) unsigned short Ks[2][KVBLK * 192]; // 2x24 KB
    __shared__ __align__(16) unsigned short Vt[128 * KVBLK];    // 16 KB
    __shared__ __align__(16) unsigned short Ps[4][16 * KVBLK];  //  8 KB (72 total)

    // job map: xcd = bid&7 (2 heads/XCD), heavy qt first within head
    const int bid = blockIdx.x;               // 0..1535
    const int xcd = bid & 7;
    const int j   = bid >> 3;                 // 0..191
    const int n   = xcd * 2 + (j >= 96);
    const int jj  = (j >= 96) ? j - 96 : j;   // 0..95
    const int qt  = 31 - (jj / NCH);
    const int ch  = jj % NCH;

    const int nt  = qt + 1;
    const int csz = (nt + NCH - 1) / NCH;
    const int tstart = ch * csz;
    if (tstart >= nt) return;                 // empty chunk
    const int tend = min(tstart + csz, nt);

    const int tid = threadIdx.x;
    const int lane = tid & 63, wid = tid >> 6;
    const int lrow = lane & 15;
    const int lkg  = lane >> 4;
    const int q0 = qt * QBLK;
    const int qrow_g = q0 + wid * 16 + lrow;  // this lane's q-row (swapped layout)
    const int pidx = ((n * 32 + qt) * NCH + ch);

    const unsigned short* Kh = Kc  + (size_t)n * 2048 * 192;
    const unsigned short* Vh = Vtc + (size_t)n * 128 * 2048;

    // ---- hoisted staging offsets ----
    int koff[6], voff[4];
    #pragma unroll
    for (int p = 0; p < 6; ++p) {
        int u = p * 256 + tid;
        int row = u / 24, c8 = u % 24;
        koff[p] = row * 192 + ((c8 ^ (row & 7)) << 3);
    }
    #pragma unroll
    for (int p = 0; p < 4; ++p) {
        int u = p * 256 + tid;
        int dv = u >> 3, c8 = u & 7;
        voff[p] = dv * 2048 + ((c8 ^ (dv & 7)) << 3);
    }

    // ---- Q fragments (B-operand; lane&15 = q-row) ----
    short8v qf[6];
    {
        const unsigned short* qrow = qb + ((size_t)qrow_g * 16 + n) * 192;
        #pragma unroll
        for (int ds = 0; ds < 6; ++ds)
            qf[ds] = *(const short8v*)(qrow + ds * 32 + lkg * 8);
    }

    f32x4 oacc[8];
    #pragma unroll
    for (int i = 0; i < 8; ++i) oacc[i] = (f32x4)0.f;
    float mrow = -3e38f;   // running max for q-row = lane&15 (full-row after combine)
    float lsum = 0.f;

    // ---- prologue: issue K[tstart] (6) then V[tstart] (4) ----
    #pragma unroll
    for (int p = 0; p < 6; ++p)
        gload16(Kh + (size_t)tstart * KVBLK * 192 + koff[p], Ks[0] + (p * 256 + wid * 64) * 8);
    #pragma unroll
    for (int p = 0; p < 4; ++p)
        gload16(Vh + tstart * KVBLK + voff[p], Vt + (p * 256 + wid * 64) * 8);

    int buf = 0;
    for (int tile = tstart; tile < tend; ++tile) {
        const int s0 = tile * KVBLK;
        const bool more = (tile + 1 < tend);

        // ---- issue K[t+1] at tile TOP (full-tile latency depth) ----
        if (more) {
            #pragma unroll
            for (int p = 0; p < 6; ++p)
                gload16(Kh + (size_t)(s0 + KVBLK) * 192 + koff[p],
                        Ks[buf ^ 1] + (p * 256 + wid * 64) * 8);
            asm volatile("s_waitcnt vmcnt(10)" ::: "memory");  // K[t] landed
        } else {
            asm volatile("s_waitcnt vmcnt(4)" ::: "memory");
        }
        __builtin_amdgcn_s_barrier();

        // ---- S^T = K Q^T : sacc[ct][j] = S[key=s0+ct*16+lkg*4+j][qrow=lane&15] ----
        f32x4 sacc[4];
        #pragma unroll
        for (int ct = 0; ct < 4; ++ct) sacc[ct] = (f32x4)0.f;
        __builtin_amdgcn_s_setprio(1);
        #pragma unroll
        for (int ds = 0; ds < 6; ++ds) {
            #pragma unroll
            for (int ct = 0; ct < 4; ++ct) {
                int krow = ct * 16 + lrow;
                int byte = (krow * 384 + ds * 64 + lkg * 16) ^ ((krow & 7) << 4);
                short8v kf = *(const short8v*)((char*)Ks[buf] + byte);
                sacc[ct] = __builtin_amdgcn_mfma_f32_16x16x32_bf16(kf, qf[ds], sacc[ct], 0, 0, 0);
            }
        }
        __builtin_amdgcn_s_setprio(0);

        // ---- causal mask: D-row = key, D-col = q-row ----
        #pragma unroll
        for (int ct = 0; ct < 4; ++ct) {
            #pragma unroll
            for (int jq = 0; jq < 4; ++jq) {
                int key = s0 + ct * 16 + lkg * 4 + jq;
                if (key > qrow_g) sacc[ct][jq] = -3e38f;
            }
        }

        // ---- in-lane softmax: 16 values for ONE q-row + 2 shfl ----
        float tm = -3e38f;
        #pragma unroll
        for (int ct = 0; ct < 4; ++ct) {
            float a = fmaxf(sacc[ct][0], sacc[ct][1]);
            float b = fmaxf(sacc[ct][2], sacc[ct][3]);
            tm = fmaxf(tm, fmaxf(a, b));
        }
        tm = fmaxf(tm, __shfl_xor(tm, 16, 64));
        tm = fmaxf(tm, __shfl_xor(tm, 32, 64));

        const bool grow = !__all(tm <= mrow);   // defer-max: skip rescale if no growth
        float corr = 1.f;
        if (grow) {
            float mn = fmaxf(mrow, tm);
            corr = __expf(mrow - mn);
            mrow = mn;
        }

        float psum = 0.f;
        unsigned short pb[4][4];
        #pragma unroll
        for (int ct = 0; ct < 4; ++ct)
            #pragma unroll
            for (int jq = 0; jq < 4; ++jq) {
                float sv = sacc[ct][jq];
                float p = (sv > -1e37f) ? __expf(sv - mrow) : 0.f;
                psum += p;
                pb[ct][jq] = f2bf(p);
            }
        psum += __shfl_xor(psum, 16, 64);
        psum += __shfl_xor(psum, 32, 64);
        lsum = grow ? (lsum * corr + psum) : (lsum + psum);

        if (grow) {
            // redistribute corr (held at lane&15==qrow) to acc-row index lkg*4+j
            float corr4[4];
            #pragma unroll
            for (int jq = 0; jq < 4; ++jq)
                corr4[jq] = __shfl(corr, (lane & 48) | (lkg * 4 + jq), 64);
            #pragma unroll
            for (int dt = 0; dt < 8; ++dt)
                #pragma unroll
                for (int jq = 0; jq < 4; ++jq) oacc[dt][jq] *= corr4[jq];
        }

        // ---- P -> per-wave LDS: row=qrow (lane&15), 4 consecutive keys per ct ----
        #pragma unroll
        for (int ct = 0; ct < 4; ++ct) {
            int c0k = ct * 16 + lkg * 4;
            int byte = ((lrow * 64 + c0k) * 2) ^ ((lrow & 7) << 4);
            uint2 w;
            w.x = (unsigned)pb[ct][0] | ((unsigned)pb[ct][1] << 16);
            w.y = (unsigned)pb[ct][2] | ((unsigned)pb[ct][3] << 16);
            *(uint2*)((char*)Ps[wid] + byte) = w;
        }

        // ---- V[t] landed (K[t+1] stays in flight) ----
        if (more) asm volatile("s_waitcnt vmcnt(6)" ::: "memory");
        else      asm volatile("s_waitcnt vmcnt(0)" ::: "memory");
        __builtin_amdgcn_s_barrier();

        // ---- O += P V ----
        __builtin_amdgcn_s_setprio(1);
        #pragma unroll
        for (int ks = 0; ks < 2; ++ks) {
            int abyte = ((lrow * 64 + ks * 32 + lkg * 8) * 2) ^ ((lrow & 7) << 4);
            short8v af = *(const short8v*)((char*)Ps[wid] + abyte);
            #pragma unroll
            for (int dt = 0; dt < 8; ++dt) {
                int vrow = dt * 16 + lrow;
                int byte = ((vrow * 128 + ks * 64 + lkg * 16)) ^ ((vrow & 7) << 4);
                short8v bf = *(const short8v*)((char*)Vt + byte);
                oacc[dt] = __builtin_amdgcn_mfma_f32_16x16x32_bf16(af, bf, oacc[dt], 0, 0, 0);
            }
        }
        __builtin_amdgcn_s_setprio(0);

        __builtin_amdgcn_s_barrier();      // Vt consumed by all waves
        // ---- issue V[t+1] (lands under next tile's QK^T+softmax) ----
        if (more) {
            #pragma unroll
            for (int p = 0; p < 4; ++p)
                gload16(Vh + (s0 + KVBLK) + voff[p], Vt + (p * 256 + wid * 64) * 8);
        }
        buf ^= 1;
    }

    // ---- write partials (unnormalized O bf16, m/l fp32) ----
    #pragma unroll
    for (int dt = 0; dt < 8; ++dt)
        #pragma unroll
        for (int jq = 0; jq < 4; ++jq) {
            int row = wid * 16 + lkg * 4 + jq;
            Opart[(size_t)pidx * 8192 + row * 128 + dt * 16 + lrow] = f2bf(oacc[dt][jq]);
        }
    if (lkg == 0)
        Ml[(size_t)pidx * 64 + wid * 16 + lrow] = make_float2(mrow, lsum);
}

// -------- combine <=3 partials per (head, qtile) -> bf16 attention out --------
__global__ __launch_bounds__(256) void attn_combine(
    const unsigned short* __restrict__ Opart, const float2* __restrict__ Ml,
    unsigned short* __restrict__ aob)
{
    const int bid = blockIdx.x;               // 512 = head*32 + qt
    const int head = bid >> 5, qt = bid & 31;
    const int nt = qt + 1, csz = (nt + NCH - 1) / NCH;
    const int nch = (nt + csz - 1) / csz;
    const int tid = threadIdx.x;
    const int r = tid >> 2, qc = tid & 3;     // row 0..63, col-quarter
    const int base = (head * 32 + qt) * NCH;

    float mi[NCH], li[NCH];
    float m = -3e38f;
    #pragma unroll
    for (int i = 0; i < NCH; ++i) {
        mi[i] = -3e38f; li[i] = 0.f;
        if (i < nch) {
            float2 v = Ml[(size_t)(base + i) * 64 + r];
            mi[i] = v.x; li[i] = v.y;
            m = fmaxf(m, v.x);
        }
    }
    float acc[32];
    #pragma unroll
    for (int u = 0; u < 32; ++u) acc[u] = 0.f;
    float l = 0.f;
    #pragma unroll
    for (int i = 0; i < NCH; ++i) {
        if (i < nch) {
            float w = __expf(mi[i] - m);
            l += w * li[i];
            const unsigned short* op = Opart + (size_t)(base + i) * 8192 + r * 128 + qc * 32;
            #pragma unroll
            for (int u = 0; u < 4; ++u) {
                short8v v8 = *(const short8v*)(op + u * 8);
                #pragma unroll
                for (int e = 0; e < 8; ++e)
                    acc[u * 8 + e] += w * __uint_as_float(((unsigned)(unsigned short)v8[e]) << 16);
            }
        }
    }
    float invl = 1.0f / l;
    unsigned short* dst = aob + (size_t)(qt * 64 + r) * 2048 + head * 128 + qc * 32;
    #pragma unroll
    for (int u = 0; u < 4; ++u) {
        short8v o8;
        #pragma unroll
        for (int e = 0; e < 8; ++e) o8[e] = (short)f2bf(acc[u * 8 + e] * invl);
        *(short8v*)(dst + u * 8) = o8;
    }
}

extern "C" void kernel_launch(void* const* d_in, const int* in_sizes, int n_in,
                              void* d_out, int out_size, void* d_ws, size_t ws_size,
                              hipStream_t stream)
{
    const float* x         = (const float*)d_in[0];
    const int*   positions = (const int*)  d_in[1];
    const float* w_q_a     = (const float*)d_in[2];
    const float* q_a_norm  = (const float*)d_in[3];
    const float* w_q_b     = (const float*)d_in[4];
    const float* w_kv_a    = (const float*)d_in[5];
    const float* kv_a_norm = (const float*)d_in[6];
    const float* w_kv_b    = (const float*)d_in[7];
    const float* w_o       = (const float*)d_in[8];
    float* out = (float*)d_out;

    // ---- workspace layout (~85.4 MB) ----
    float* q   = (float*)d_ws;                          // 2048*3072 f32 (later Kc/Vtc)
    float* kv  = q + (size_t)2048 * 3072;               // 2048*576 f32
    unsigned short* kvbb = (unsigned short*)(kv + (size_t)2048 * 576); // 2048*4096 bf16
    float* q_c = (float*)kvbb;                          // alias (dead before kvbb use)
    unsigned short* q_cb  = kvbb + (size_t)2048 * 4096; // 2048*1536
    unsigned short* kv_cb = q_cb + (size_t)2048 * 1536; // 2048*512
    unsigned short* xb    = kv_cb + (size_t)2048 * 512; // 2048*2048
    unsigned short* aob   = xb;                         // alias (xb dead before attn)
    unsigned short* qb    = xb + (size_t)2048 * 2048;   // 2048*16*192
    unsigned short* wbuf  = qb + (size_t)2048 * 3072;   // 3072*1536 max
    unsigned short* Kc    = (unsigned short*)q;         // 16*2048*192 (q dead after rope_qb)
    unsigned short* Vtc   = Kc + (size_t)16 * 2048 * 192; // 16*128*2048
    // partial scratch overlays kv+kvbb+q_cb+kv_cb (all dead by attn time): 29.9 MB
    unsigned short* Opart = (unsigned short*)kv;        // 1536*8192 bf16 = 25.2 MB
    float2* Ml = (float2*)(Opart + (size_t)1536 * 8192);// 1536*64*8B = 0.8 MB

    dim3 blk(256);

    // x -> bf16
    conv_bf16<<<(2048 * 2048 / 4 + 255) / 256, blk, 0, stream>>>(x, xb, 2048 * 2048 / 4);

    // G1: q_c = x @ w_q_a   (N=1536, K=2048) fp32 out
    wt_bf16<<<dim3(1536 / 32, 2048 / 32), blk, 0, stream>>>(w_q_a, wbuf, 2048, 1536);
    gemm_bf16<false><<<dim3(1536 / 128, 16), blk, 0, stream>>>(xb, wbuf, q_c, 1536, 2048, 1536);
    rmsnorm_bf16<<<2048, blk, 0, stream>>>(q_c, q_a_norm, q_cb, 1536);

    // G2: q = q_cb @ w_q_b  (N=3072, K=1536) fp32 out; then rope+pack -> qb
    wt_bf16<<<dim3(3072 / 32, 1536 / 32), blk, 0, stream>>>(w_q_b, wbuf, 1536, 3072);
    gemm_bf16<false><<<dim3(3072 / 128, 16), blk, 0, stream>>>(q_cb, wbuf, q, 3072, 1536, 3072);
    rope_qb<<<2048, dim3(192), 0, stream>>>(q, positions, qb);   // q dead after

    // G3: kv = x @ w_kv_a   (N=576, K=2048) fp32 out
    wt_bf16<<<dim3(576 / 32, 2048 / 32), blk, 0, stream>>>(w_kv_a, wbuf, 2048, 576);
    gemm_bf16<false><<<dim3(5, 16), blk, 0, stream>>>(xb, wbuf, kv, 576, 2048, 576);
    kv_fuse<<<2048, blk, 0, stream>>>(kv, kv_a_norm, positions, kv_cb);

    // G4: kvbb = kv_cb @ w_kv_b  (N=4096, K=512) bf16 out
    wt_bf16<<<dim3(4096 / 32, 512 / 32), blk, 0, stream>>>(w_kv_b, wbuf, 512, 4096);
    gemm_bf16<true><<<dim3(4096 / 128, 16), blk, 0, stream>>>(kv_cb, wbuf, kvbb, 4096, 512, 4096);

    // repack K and V^T caches (overwrites q's space)
    repack_k<<<2048, blk, 0, stream>>>(kvbb, kv, Kc);
    repack_vt<<<dim3(32, 32), blk, 0, stream>>>(kvbb, Vtc);

    // attention: 1536 KV-split jobs, swapped-QK^T in-lane softmax + combine
    attn_part<<<1536, blk, 0, stream>>>(qb, Kc, Vtc, Opart, Ml);
    attn_combine<<<512, blk, 0, stream>>>(Opart, Ml, aob);

    // G5: out = aob @ w_o   (N=2048, K=2048) fp32 out
    wt_bf16<<<dim3(2048 / 32, 2048 / 32), blk, 0, stream>>>(w_o, wbuf, 2048, 2048);
    gemm_bf16<false><<<dim3(2048 / 128, 16), blk, 0, stream>>>(aob, wbuf, out, 2048, 2048, 2048);
}